// Round 14
// baseline (1213.449 us; speedup 1.0000x reference)
//
#include <hip/hip_runtime.h>
#include <math.h>

#define HID 256
#define PI_F 3.14159265358979323846f
#define INF_BITS 0x7f800000u

struct F3 { float x, y, z; };

// ---- XLA-gfx950 emulation ----
// crosses: CONTRACTED, pinned to LLVM-canonical fma(a.y,b.z, -(a.z*b.y))
// dots / sums-of-squares: CLEAN (XLA reduce does not contract), (x+y)+z order
// sqrt: correctly rounded (via f64)
__device__ __forceinline__ F3 crossc(F3 a, F3 b) {
    F3 r;
    float t1 = a.z * b.y;
    r.x = __builtin_fmaf(a.y, b.z, -t1);
    float t2 = a.x * b.z;
    r.y = __builtin_fmaf(a.z, b.x, -t2);
    float t3 = a.y * b.x;
    r.z = __builtin_fmaf(a.x, b.y, -t3);
    return r;
}
__device__ __forceinline__ float dotf(F3 a, F3 b) {
#pragma clang fp contract(off)
    float px = a.x * b.x;
    float py = a.y * b.y;
    float pz = a.z * b.z;
    return (px + py) + pz;
}
__device__ __forceinline__ float sqrt_cr(float ss) {
    return (float)sqrt((double)ss);   // correctly-rounded f32 sqrt
}
__device__ __forceinline__ float safe_atan2(float b, float a) {
    float aa = (a == 0.f && b == 0.f) ? 1.f : a;
    return atan2f(b, aa);
}
__device__ __forceinline__ F3 loadp(const float* __restrict__ pos, int n) {
    F3 r;
    r.x = pos[3 * n + 0];
    r.y = pos[3 * n + 1];
    r.z = pos[3 * n + 2];
    return r;
}
__device__ __forceinline__ F3 subv(F3 a, F3 b) {
#pragma clang fp contract(off)
    F3 r;
    r.x = a.x - b.x;
    r.y = a.y - b.y;
    r.z = a.z - b.z;
    return r;
}

// ---------------- dist: CLEAN (no FMA) + CR sqrt == XLA reduce bits ----------------
__global__ void k_dist(const int* __restrict__ ei, const int* __restrict__ ej,
                       const float* __restrict__ pos, float* __restrict__ dist, int E) {
#pragma clang fp contract(off)
    int e = blockIdx.x * blockDim.x + threadIdx.x;
    if (e >= E) return;
    F3 v = subv(loadp(pos, ej[e]), loadp(pos, ei[e]));
    float sx = v.x * v.x;
    float sy = v.y * v.y;
    float sz = v.z * v.z;
    float ss = (sx + sy) + sz;
    dist[e] = (ss == 0.f) ? 0.f : sqrt_cr(ss);
}

// ---------------- two-pass segment-argmin (value, then index among equals) ----------------
__global__ void k_init_min(unsigned* __restrict__ minvA, int* __restrict__ miniA,
                           unsigned* __restrict__ minvB, int* __restrict__ miniB, int N) {
    int n = blockIdx.x * blockDim.x + threadIdx.x;
    if (n >= N) return;
    minvA[n] = INF_BITS; miniA[n] = 0x7fffffff;
    minvB[n] = INF_BITS; miniB[n] = 0x7fffffff;
}
__global__ void k_minval(const int* __restrict__ ei, const int* __restrict__ ej,
                         const float* __restrict__ dA, const float* __restrict__ dB,
                         unsigned* __restrict__ minvA, unsigned* __restrict__ minvB, int E) {
    int e = blockIdx.x * blockDim.x + threadIdx.x;
    if (e >= E) return;
    atomicMin(&minvA[ei[e]], __float_as_uint(dA[e]));
    atomicMin(&minvB[ej[e]], __float_as_uint(dB[e]));
}
__global__ void k_minidx(const int* __restrict__ ei, const int* __restrict__ ej,
                         const float* __restrict__ dA, const float* __restrict__ dB,
                         const unsigned* __restrict__ minvA, int* __restrict__ miniA,
                         const unsigned* __restrict__ minvB, int* __restrict__ miniB, int E) {
    int e = blockIdx.x * blockDim.x + threadIdx.x;
    if (e >= E) return;
    int ii = ei[e], jj = ej[e];
    if (__float_as_uint(dA[e]) == minvA[ii]) atomicMin(&miniA[ii], e);
    if (__float_as_uint(dB[e]) == minvB[jj]) atomicMin(&miniB[jj], e);
}
__global__ void k_extract(unsigned* __restrict__ minvA, int* __restrict__ miniA,
                          unsigned* __restrict__ minvB, int* __restrict__ miniB,
                          int* __restrict__ aA, int* __restrict__ aB,
                          int N, int E, int reinit) {
    int n = blockIdx.x * blockDim.x + threadIdx.x;
    if (n >= N) return;
    int mA = miniA[n];
    aA[n] = (mA >= E) ? 0 : mA;
    int mB = miniB[n];
    aB[n] = (mB >= E) ? 0 : mB;
    if (reinit) {
        minvA[n] = INF_BITS; miniA[n] = 0x7fffffff;
        minvB[n] = INF_BITS; miniB[n] = 0x7fffffff;
    }
}
// dist1 = dist + zeros.at[argmin0].set(8.0), literal add-semantics
__global__ void k_copy(const float* __restrict__ dist, float* __restrict__ d1A,
                       float* __restrict__ d1B, int E) {
    int e = blockIdx.x * blockDim.x + threadIdx.x;
    if (e >= E) return;
    float d = dist[e];
    d1A[e] = d;
    d1B[e] = d;
}
__global__ void k_mark(const float* __restrict__ dist, const int* __restrict__ a0i,
                       const int* __restrict__ a0j, float* __restrict__ d1A,
                       float* __restrict__ d1B, int N) {
#pragma clang fp contract(off)
    int n = blockIdx.x * blockDim.x + threadIdx.x;
    if (n >= N) return;
    int eA = a0i[n];
    d1A[eA] = dist[eA] + 8.0f;
    int eB = a0j[n];
    d1B[eB] = dist[eB] + 8.0f;
}

// ---------------- angles: contracted crosses + clean dots (XLA mix) ----------------
__global__ void k_angles(const int* __restrict__ ei, const int* __restrict__ ej,
                         const float* __restrict__ pos, const float* __restrict__ dist,
                         const int* __restrict__ a0i, const int* __restrict__ a1i,
                         const int* __restrict__ a0j, const int* __restrict__ a1j,
                         float* __restrict__ theta, float* __restrict__ phi,
                         float* __restrict__ tau, int E) {
    int e = blockIdx.x * blockDim.x + threadIdx.x;
    if (e >= E) return;
    int ii = ei[e], jj = ej[e];
    int e0i = a0i[ii];
    int e1i = a1i[ii];
    int e0j = a0j[jj];
    int e1j = a1j[jj];

    int n0 = ej[e0i];    // j[argmin0][i]
    int n0j = ei[e0j];   // i[argmin0_j][j]
    int eiref = (n0 == jj) ? e1i : e0i;
    int ejref = (n0j == ii) ? e1j : e0j;

    F3 p = subv(loadp(pos, jj), loadp(pos, ii));                  // pos_ji
    F3 in0 = subv(loadp(pos, ej[e0i]), loadp(pos, ei[e0i]));
    F3 in1 = subv(loadp(pos, ej[e1i]), loadp(pos, ei[e1i]));
    F3 iref = subv(loadp(pos, ej[eiref]), loadp(pos, ei[eiref]));
    F3 jref = subv(loadp(pos, ej[ejref]), loadp(pos, ei[ejref]));
    F3 mp;
    mp.x = -p.x; mp.y = -p.y; mp.z = -p.z;

    // theta = atan2(||cross(-p,in0)||, dot(-p,in0))
    float a = dotf(mp, in0);
    F3 c1 = crossc(mp, in0);       // = plane1 for phi
    float ssb = dotf(c1, c1);
    float b = (ssb == 0.f) ? 0.f : sqrt_cr(ssb);
    float th = safe_atan2(b, a);
    if (th < 0.f) th += PI_F;

    float dji = dist[e];

    // phi
    F3 pl2 = crossc(mp, in1);
    a = dotf(c1, pl2);
    F3 cc = crossc(c1, pl2);
    b = dotf(cc, p) / dji;
    float ph = safe_atan2(b, a);
    if (ph < 0.f) ph += PI_F;

    // tau
    F3 t1 = crossc(p, jref);
    F3 t2 = crossc(p, iref);
    a = dotf(t1, t2);
    cc = crossc(t1, t2);
    b = dotf(cc, p) / dji;
    float ta = safe_atan2(b, a);
    if (ta < 0.f) ta += PI_F;

    theta[e] = th;
    phi[e] = ph;
    tau[e] = ta;
}

// ---------------- embedding + swish (runs LAST: overwrites scratch) ----------------
__global__ void k_embed(const int* __restrict__ x, const float* __restrict__ w,
                        float* __restrict__ h, int total4) {
    int t = blockIdx.x * blockDim.x + threadIdx.x;
    if (t >= total4) return;
    int n = t >> 6;
    int c = t & 63;
    int row = x[n];
    float4 v = *reinterpret_cast<const float4*>(w + (size_t)row * HID + c * 4);
    float4 o;
    o.x = v.x / (1.f + expf(-v.x));
    o.y = v.y / (1.f + expf(-v.y));
    o.z = v.z / (1.f + expf(-v.z));
    o.w = v.w / (1.f + expf(-v.w));
    *reinterpret_cast<float4*>(h + (size_t)n * HID + c * 4) = o;
}

extern "C" void kernel_launch(void* const* d_in, const int* in_sizes, int n_in,
                              void* d_out, int out_size, void* d_ws, size_t ws_size,
                              hipStream_t stream) {
    const int* x = (const int*)d_in[0];
    const float* pos = (const float*)d_in[1];
    const int* eidx = (const int*)d_in[2];
    const float* emb = (const float*)d_in[3];

    const int N = in_sizes[0];
    const int E = in_sizes[2] / 2;
    const int* ei = eidx;
    const int* ej = eidx + E;

    float* out = (float*)d_out;
    float* out_h = out;
    float* out_dist = out + (size_t)N * HID;
    float* out_theta = out_dist + E;
    float* out_phi = out_theta + E;
    float* out_tau = out_phi + E;

    // scratch lives in the h-region of d_out; k_embed runs last and overwrites it
    float* d1A = out_h;                       // E floats
    float* d1B = d1A + E;                     // E floats
    unsigned* minvA = (unsigned*)(d1B + E);   // N
    unsigned* minvB = minvA + N;              // N
    int* miniA = (int*)(minvB + N);           // N
    int* miniB = miniA + N;                   // N
    int* a0i = miniB + N;                     // N
    int* a0j = a0i + N;                       // N
    int* a1i = a0j + N;                       // N
    int* a1j = a1i + N;                       // N

    const int BS = 256;
    int gE = (E + BS - 1) / BS;
    int gN = (N + BS - 1) / BS;
    int total4 = N * (HID / 4);
    int gH = (total4 + BS - 1) / BS;

    k_dist<<<gE, BS, 0, stream>>>(ei, ej, pos, out_dist, E);

    // argmin0 over i-segments (A) and j-segments (B), on dist
    k_init_min<<<gN, BS, 0, stream>>>(minvA, miniA, minvB, miniB, N);
    k_minval<<<gE, BS, 0, stream>>>(ei, ej, out_dist, out_dist, minvA, minvB, E);
    k_minidx<<<gE, BS, 0, stream>>>(ei, ej, out_dist, out_dist, minvA, miniA, minvB, miniB, E);
    k_extract<<<gN, BS, 0, stream>>>(minvA, miniA, minvB, miniB, a0i, a0j, N, E, 1);

    // dist1 = dist + at[argmin0].set(8)
    k_copy<<<gE, BS, 0, stream>>>(out_dist, d1A, d1B, E);
    k_mark<<<gN, BS, 0, stream>>>(out_dist, a0i, a0j, d1A, d1B, N);

    // argmin1 on dist1
    k_minval<<<gE, BS, 0, stream>>>(ei, ej, d1A, d1B, minvA, minvB, E);
    k_minidx<<<gE, BS, 0, stream>>>(ei, ej, d1A, d1B, minvA, miniA, minvB, miniB, E);
    k_extract<<<gN, BS, 0, stream>>>(minvA, miniA, minvB, miniB, a1i, a1j, N, E, 0);

    k_angles<<<gE, BS, 0, stream>>>(ei, ej, pos, out_dist, a0i, a1i, a0j, a1j,
                                    out_theta, out_phi, out_tau, E);
    k_embed<<<gH, BS, 0, stream>>>(x, emb, out_h, total4);
}

// Round 15
// 690.821 us; speedup vs baseline: 1.7565x; 1.7565x over previous
//
#include <hip/hip_runtime.h>
#include <math.h>

#define HID 256
#define PI_F 3.14159265358979323846f
typedef unsigned long long ull;

struct F3 { float x, y, z; };

// ---- LOCKED NUMERICS (passing recipe, R14): clean dist (no FMA, numpy order,
// CR sqrt) + contracted crosses (fma(a.y,b.z,-(a.z*b.y))) + clean dots ----
__device__ __forceinline__ F3 crossc(F3 a, F3 b) {
    F3 r;
    float t1 = a.z * b.y;
    r.x = __builtin_fmaf(a.y, b.z, -t1);
    float t2 = a.x * b.z;
    r.y = __builtin_fmaf(a.z, b.x, -t2);
    float t3 = a.y * b.x;
    r.z = __builtin_fmaf(a.x, b.y, -t3);
    return r;
}
__device__ __forceinline__ float dotf(F3 a, F3 b) {
#pragma clang fp contract(off)
    float px = a.x * b.x;
    float py = a.y * b.y;
    float pz = a.z * b.z;
    return (px + py) + pz;
}
__device__ __forceinline__ float sqrt_cr(float ss) {
    return (float)sqrt((double)ss);
}
__device__ __forceinline__ float safe_atan2(float b, float a) {
    float aa = (a == 0.f && b == 0.f) ? 1.f : a;
    return atan2f(b, aa);
}
__device__ __forceinline__ F3 loadp(const float* __restrict__ pos, int n) {
    F3 r;
    r.x = pos[3 * n + 0];
    r.y = pos[3 * n + 1];
    r.z = pos[3 * n + 2];
    return r;
}
__device__ __forceinline__ F3 subv(F3 a, F3 b) {
#pragma clang fp contract(off)
    F3 r;
    r.x = a.x - b.x;
    r.y = a.y - b.y;
    r.z = a.z - b.z;
    return r;
}

// ---------------- init ----------------
__global__ void k_init(ull* __restrict__ minA, ull* __restrict__ minB,
                       unsigned* __restrict__ flags, int N) {
    int n = blockIdx.x * blockDim.x + threadIdx.x;
    if (n < N) {
        minA[n] = ~0ull;
        minB[n] = ~0ull;
    }
    if (n == 0) {
        flags[0] = 0u;
        flags[1] = 0u;
    }
}

// ---------------- pass1: dist (locked numerics) + packed argmin0 ----------------
__global__ void k_pass1(const int* __restrict__ ei, const int* __restrict__ ej,
                        const float* __restrict__ pos, float* __restrict__ dist,
                        ull* __restrict__ minA, ull* __restrict__ minB, int E) {
#pragma clang fp contract(off)
    int e = blockIdx.x * blockDim.x + threadIdx.x;
    if (e >= E) return;
    int ii = ei[e], jj = ej[e];
    F3 v = subv(loadp(pos, jj), loadp(pos, ii));
    float sx = v.x * v.x;
    float sy = v.y * v.y;
    float sz = v.z * v.z;
    float ss = (sx + sy) + sz;
    float d = (ss == 0.f) ? 0.f : sqrt_cr(ss);
    dist[e] = d;
    // packed (distbits, idx): lex-min == (min dist, tie -> min index) == ref
    ull key = ((ull)__float_as_uint(d) << 32) | (unsigned)e;
    atomicMin(&minA[ii], key);
    atomicMin(&minB[jj], key);
}

// ---------------- extract0: unpack, set empty-flags, reset for pass2 ----------------
__global__ void k_extract0(ull* __restrict__ minA, ull* __restrict__ minB,
                           int* __restrict__ a0i, int* __restrict__ a0j,
                           unsigned* __restrict__ flags, int N) {
    int n = blockIdx.x * blockDim.x + threadIdx.x;
    if (n >= N) return;
    ull kA = minA[n];
    if (kA == ~0ull) { a0i[n] = 0; atomicOr(&flags[0], 1u); }
    else             { a0i[n] = (int)(kA & 0xffffffffu); }
    ull kB = minB[n];
    if (kB == ~0ull) { a0j[n] = 0; atomicOr(&flags[1], 1u); }
    else             { a0j[n] = (int)(kB & 0xffffffffu); }
    minA[n] = ~0ull;
    minB[n] = ~0ull;
}

// ---------------- pass2: packed argmin1 on dist1 = dist + 8*mark ----------------
// mark(e) == (a0i[ei[e]]==e) || (e==0 && any-empty-A-segment)  — literal ref semantics
__global__ void k_pass2(const int* __restrict__ ei, const int* __restrict__ ej,
                        const float* __restrict__ dist, const int* __restrict__ a0i,
                        const int* __restrict__ a0j, const unsigned* __restrict__ flags,
                        ull* __restrict__ minA, ull* __restrict__ minB, int E) {
#pragma clang fp contract(off)
    int e = blockIdx.x * blockDim.x + threadIdx.x;
    if (e >= E) return;
    int ii = ei[e], jj = ej[e];
    float d = dist[e];
    bool inA = (a0i[ii] == e) || (e == 0 && flags[0] != 0u);
    float dA = inA ? (d + 8.0f) : d;
    atomicMin(&minA[ii], ((ull)__float_as_uint(dA) << 32) | (unsigned)e);
    bool inB = (a0j[jj] == e) || (e == 0 && flags[1] != 0u);
    float dB = inB ? (d + 8.0f) : d;
    atomicMin(&minB[jj], ((ull)__float_as_uint(dB) << 32) | (unsigned)e);
}

// ---------------- extract1 + per-node vector precompute ----------------
// nodeA0[n] = {in0.xyz, bits(n0)}   in0 = vec(a0i[n]), n0 = ej[a0i[n]]
// nodeA1[n] = {in1.xyz, 0}          in1 = vec(a1i[n])
// nodeB0[n] = {w0.xyz,  bits(m0)}   w0  = vec(a0j[n]), m0 = ei[a0j[n]]
// nodeB1[n] = {w1.xyz,  0}          w1  = vec(a1j[n])
__global__ void k_extract1_prep(const ull* __restrict__ minA, const ull* __restrict__ minB,
                                const int* __restrict__ a0i, const int* __restrict__ a0j,
                                const int* __restrict__ ei, const int* __restrict__ ej,
                                const float* __restrict__ pos,
                                float4* __restrict__ nodeA0, float4* __restrict__ nodeA1,
                                float4* __restrict__ nodeB0, float4* __restrict__ nodeB1,
                                int N) {
    int n = blockIdx.x * blockDim.x + threadIdx.x;
    if (n >= N) return;
    ull kA = minA[n];
    int a1A = (kA == ~0ull) ? 0 : (int)(kA & 0xffffffffu);
    ull kB = minB[n];
    int a1B = (kB == ~0ull) ? 0 : (int)(kB & 0xffffffffu);

    int e0 = a0i[n];
    F3 in0 = subv(loadp(pos, ej[e0]), loadp(pos, ei[e0]));
    int n0 = ej[e0];
    F3 in1 = subv(loadp(pos, ej[a1A]), loadp(pos, ei[a1A]));

    int f0 = a0j[n];
    F3 w0 = subv(loadp(pos, ej[f0]), loadp(pos, ei[f0]));
    int m0 = ei[f0];
    F3 w1 = subv(loadp(pos, ej[a1B]), loadp(pos, ei[a1B]));

    nodeA0[n] = make_float4(in0.x, in0.y, in0.z, __int_as_float(n0));
    nodeA1[n] = make_float4(in1.x, in1.y, in1.z, 0.f);
    nodeB0[n] = make_float4(w0.x, w0.y, w0.z, __int_as_float(m0));
    nodeB1[n] = make_float4(w1.x, w1.y, w1.z, 0.f);
}

// ---------------- angles: node-array gathers (L2-resident), locked numerics ----------------
__global__ void k_angles(const int* __restrict__ ei, const int* __restrict__ ej,
                         const float* __restrict__ pos, const float* __restrict__ dist,
                         const float4* __restrict__ nodeA0, const float4* __restrict__ nodeA1,
                         const float4* __restrict__ nodeB0, const float4* __restrict__ nodeB1,
                         float* __restrict__ theta, float* __restrict__ phi,
                         float* __restrict__ tau, int E) {
    int e = blockIdx.x * blockDim.x + threadIdx.x;
    if (e >= E) return;
    int ii = ei[e], jj = ej[e];

    float4 A0 = nodeA0[ii];
    float4 A1 = nodeA1[ii];
    float4 B0 = nodeB0[jj];
    float4 B1 = nodeB1[jj];
    int n0 = __float_as_int(A0.w);    // j[argmin0][i]
    int m0 = __float_as_int(B0.w);    // i[argmin0_j][j]

    F3 in0; in0.x = A0.x; in0.y = A0.y; in0.z = A0.z;
    F3 in1; in1.x = A1.x; in1.y = A1.y; in1.z = A1.z;
    F3 w0;  w0.x = B0.x;  w0.y = B0.y;  w0.z = B0.z;
    F3 w1;  w1.x = B1.x;  w1.y = B1.y;  w1.z = B1.z;

    F3 iref = (n0 == jj) ? in1 : in0;
    F3 jref = (m0 == ii) ? w1 : w0;

    F3 p = subv(loadp(pos, jj), loadp(pos, ii));    // pos_ji (pos is L2-resident)
    F3 mp;
    mp.x = -p.x; mp.y = -p.y; mp.z = -p.z;

    // theta
    float a = dotf(mp, in0);
    F3 c1 = crossc(mp, in0);
    float ssb = dotf(c1, c1);
    float b = (ssb == 0.f) ? 0.f : sqrt_cr(ssb);
    float th = safe_atan2(b, a);
    if (th < 0.f) th += PI_F;

    float dji = dist[e];

    // phi
    F3 pl2 = crossc(mp, in1);
    a = dotf(c1, pl2);
    F3 cc = crossc(c1, pl2);
    b = dotf(cc, p) / dji;
    float ph = safe_atan2(b, a);
    if (ph < 0.f) ph += PI_F;

    // tau
    F3 t1 = crossc(p, jref);
    F3 t2 = crossc(p, iref);
    a = dotf(t1, t2);
    cc = crossc(t1, t2);
    b = dotf(cc, p) / dji;
    float ta = safe_atan2(b, a);
    if (ta < 0.f) ta += PI_F;

    theta[e] = th;
    phi[e] = ph;
    tau[e] = ta;
}

// ---------------- embedding + swish (runs LAST: overwrites scratch) ----------------
__global__ void k_embed(const int* __restrict__ x, const float* __restrict__ w,
                        float* __restrict__ h, int total4) {
    int t = blockIdx.x * blockDim.x + threadIdx.x;
    if (t >= total4) return;
    int n = t >> 6;
    int c = t & 63;
    int row = x[n];
    float4 v = *reinterpret_cast<const float4*>(w + (size_t)row * HID + c * 4);
    float4 o;
    o.x = v.x / (1.f + expf(-v.x));
    o.y = v.y / (1.f + expf(-v.y));
    o.z = v.z / (1.f + expf(-v.z));
    o.w = v.w / (1.f + expf(-v.w));
    *reinterpret_cast<float4*>(h + (size_t)n * HID + c * 4) = o;
}

extern "C" void kernel_launch(void* const* d_in, const int* in_sizes, int n_in,
                              void* d_out, int out_size, void* d_ws, size_t ws_size,
                              hipStream_t stream) {
    const int* x = (const int*)d_in[0];
    const float* pos = (const float*)d_in[1];
    const int* eidx = (const int*)d_in[2];
    const float* emb = (const float*)d_in[3];

    const int N = in_sizes[0];
    const int E = in_sizes[2] / 2;
    const int* ei = eidx;
    const int* ej = eidx + E;

    float* out = (float*)d_out;
    float* out_h = out;
    float* out_dist = out + (size_t)N * HID;
    float* out_theta = out_dist + E;
    float* out_phi = out_theta + E;
    float* out_tau = out_phi + E;

    // scratch in h-region of d_out (102 MB >> 10 MB needed); k_embed runs last.
    // Layout (d_out is 256B-aligned): minA/minB (8B), node float4 arrays (16B),
    // then int arrays + flags.
    ull* minA = (ull*)out_h;                      // N
    ull* minB = minA + N;                         // N
    float4* nodeA0 = (float4*)(minB + N);         // N  (16N bytes offset: 16-aligned)
    float4* nodeA1 = nodeA0 + N;
    float4* nodeB0 = nodeA1 + N;
    float4* nodeB1 = nodeB0 + N;
    int* a0i = (int*)(nodeB1 + N);                // N
    int* a0j = a0i + N;                           // N
    unsigned* flags = (unsigned*)(a0j + N);       // 2

    const int BS = 256;
    int gE = (E + BS - 1) / BS;
    int gN = (N + BS - 1) / BS;
    int total4 = N * (HID / 4);
    int gH = (total4 + BS - 1) / BS;

    k_init<<<gN, BS, 0, stream>>>(minA, minB, flags, N);
    k_pass1<<<gE, BS, 0, stream>>>(ei, ej, pos, out_dist, minA, minB, E);
    k_extract0<<<gN, BS, 0, stream>>>(minA, minB, a0i, a0j, flags, N);
    k_pass2<<<gE, BS, 0, stream>>>(ei, ej, out_dist, a0i, a0j, flags, minA, minB, E);
    k_extract1_prep<<<gN, BS, 0, stream>>>(minA, minB, a0i, a0j, ei, ej, pos,
                                           nodeA0, nodeA1, nodeB0, nodeB1, N);
    k_angles<<<gE, BS, 0, stream>>>(ei, ej, pos, out_dist,
                                    nodeA0, nodeA1, nodeB0, nodeB1,
                                    out_theta, out_phi, out_tau, E);
    k_embed<<<gH, BS, 0, stream>>>(x, emb, out_h, total4);
}

// Round 16
// 559.687 us; speedup vs baseline: 2.1681x; 1.2343x over previous
//
#include <hip/hip_runtime.h>
#include <math.h>

#define HID 256
#define PI_F 3.14159265358979323846f
typedef unsigned long long ull;

struct F3 { float x, y, z; };

// ---- LOCKED NUMERICS (passing recipe, R14): clean dist (no FMA, numpy order,
// CR sqrt) + contracted crosses (fma(a.y,b.z,-(a.z*b.y))) + clean dots ----
__device__ __forceinline__ F3 crossc(F3 a, F3 b) {
    F3 r;
    float t1 = a.z * b.y;
    r.x = __builtin_fmaf(a.y, b.z, -t1);
    float t2 = a.x * b.z;
    r.y = __builtin_fmaf(a.z, b.x, -t2);
    float t3 = a.y * b.x;
    r.z = __builtin_fmaf(a.x, b.y, -t3);
    return r;
}
__device__ __forceinline__ float dotf(F3 a, F3 b) {
#pragma clang fp contract(off)
    float px = a.x * b.x;
    float py = a.y * b.y;
    float pz = a.z * b.z;
    return (px + py) + pz;
}
__device__ __forceinline__ float sqrt_cr(float ss) {
    return (float)sqrt((double)ss);
}
__device__ __forceinline__ float safe_atan2(float b, float a) {
    float aa = (a == 0.f && b == 0.f) ? 1.f : a;
    return atan2f(b, aa);
}
__device__ __forceinline__ F3 loadp(const float* __restrict__ pos, int n) {
    F3 r;
    r.x = pos[3 * n + 0];
    r.y = pos[3 * n + 1];
    r.z = pos[3 * n + 2];
    return r;
}
__device__ __forceinline__ F3 subv(F3 a, F3 b) {
#pragma clang fp contract(off)
    F3 r;
    r.x = a.x - b.x;
    r.y = a.y - b.y;
    r.z = a.z - b.z;
    return r;
}

// filtered 64-bit atomicMin: skip when our dist bits are STRICTLY greater than
// a (possibly stale) read of the slot's hi word. Hi word is monotone
// non-increasing (lex-min), stale >= current, so strict-greater can never
// win or tie -> skip is provably safe. Ties always issue the atomic.
__device__ __forceinline__ void atomicMinFiltered(ull* slot, unsigned db, ull key) {
    const volatile unsigned* hi = ((const volatile unsigned*)slot) + 1;  // little-endian
    if (db <= *hi) atomicMin(slot, key);
}

// ---------------- init ----------------
__global__ void k_init(ull* __restrict__ minA, ull* __restrict__ minB,
                       unsigned* __restrict__ flags, int N) {
    int n = blockIdx.x * blockDim.x + threadIdx.x;
    if (n < N) {
        minA[n] = ~0ull;
        minB[n] = ~0ull;
    }
    if (n == 0) {
        flags[0] = 0u;
        flags[1] = 0u;
    }
}

// ---------------- pass1: dist (locked numerics) + filtered packed argmin0 ----------------
__global__ void k_pass1(const int* __restrict__ ei, const int* __restrict__ ej,
                        const float* __restrict__ pos, float* __restrict__ dist,
                        ull* __restrict__ minA, ull* __restrict__ minB, int E) {
#pragma clang fp contract(off)
    int e = blockIdx.x * blockDim.x + threadIdx.x;
    if (e >= E) return;
    int ii = ei[e], jj = ej[e];
    F3 v = subv(loadp(pos, jj), loadp(pos, ii));
    float sx = v.x * v.x;
    float sy = v.y * v.y;
    float sz = v.z * v.z;
    float ss = (sx + sy) + sz;
    float d = (ss == 0.f) ? 0.f : sqrt_cr(ss);
    dist[e] = d;
    unsigned db = __float_as_uint(d);
    ull key = ((ull)db << 32) | (unsigned)e;
    atomicMinFiltered(&minA[ii], db, key);
    atomicMinFiltered(&minB[jj], db, key);
}

// ---------------- extract0: unpack, set empty-flags, reset for pass2 ----------------
__global__ void k_extract0(ull* __restrict__ minA, ull* __restrict__ minB,
                           int* __restrict__ a0i, int* __restrict__ a0j,
                           unsigned* __restrict__ flags, int N) {
    int n = blockIdx.x * blockDim.x + threadIdx.x;
    if (n >= N) return;
    ull kA = minA[n];
    if (kA == ~0ull) { a0i[n] = 0; atomicOr(&flags[0], 1u); }
    else             { a0i[n] = (int)(kA & 0xffffffffu); }
    ull kB = minB[n];
    if (kB == ~0ull) { a0j[n] = 0; atomicOr(&flags[1], 1u); }
    else             { a0j[n] = (int)(kB & 0xffffffffu); }
    minA[n] = ~0ull;
    minB[n] = ~0ull;
}

// ---------------- pass2: filtered packed argmin1 on dist1 = dist + 8*mark ----------------
__global__ void k_pass2(const int* __restrict__ ei, const int* __restrict__ ej,
                        const float* __restrict__ dist, const int* __restrict__ a0i,
                        const int* __restrict__ a0j, const unsigned* __restrict__ flags,
                        ull* __restrict__ minA, ull* __restrict__ minB, int E) {
#pragma clang fp contract(off)
    int e = blockIdx.x * blockDim.x + threadIdx.x;
    if (e >= E) return;
    int ii = ei[e], jj = ej[e];
    float d = dist[e];
    bool inA = (a0i[ii] == e) || (e == 0 && flags[0] != 0u);
    float dA = inA ? (d + 8.0f) : d;
    unsigned dbA = __float_as_uint(dA);
    atomicMinFiltered(&minA[ii], dbA, ((ull)dbA << 32) | (unsigned)e);
    bool inB = (a0j[jj] == e) || (e == 0 && flags[1] != 0u);
    float dB = inB ? (d + 8.0f) : d;
    unsigned dbB = __float_as_uint(dB);
    atomicMinFiltered(&minB[jj], dbB, ((ull)dbB << 32) | (unsigned)e);
}

// ---------------- extract1 + per-node vector precompute ----------------
__global__ void k_extract1_prep(const ull* __restrict__ minA, const ull* __restrict__ minB,
                                const int* __restrict__ a0i, const int* __restrict__ a0j,
                                const int* __restrict__ ei, const int* __restrict__ ej,
                                const float* __restrict__ pos,
                                float4* __restrict__ nodeA0, float4* __restrict__ nodeA1,
                                float4* __restrict__ nodeB0, float4* __restrict__ nodeB1,
                                int N) {
    int n = blockIdx.x * blockDim.x + threadIdx.x;
    if (n >= N) return;
    ull kA = minA[n];
    int a1A = (kA == ~0ull) ? 0 : (int)(kA & 0xffffffffu);
    ull kB = minB[n];
    int a1B = (kB == ~0ull) ? 0 : (int)(kB & 0xffffffffu);

    int e0 = a0i[n];
    F3 in0 = subv(loadp(pos, ej[e0]), loadp(pos, ei[e0]));
    int n0 = ej[e0];
    F3 in1 = subv(loadp(pos, ej[a1A]), loadp(pos, ei[a1A]));

    int f0 = a0j[n];
    F3 w0 = subv(loadp(pos, ej[f0]), loadp(pos, ei[f0]));
    int m0 = ei[f0];
    F3 w1 = subv(loadp(pos, ej[a1B]), loadp(pos, ei[a1B]));

    nodeA0[n] = make_float4(in0.x, in0.y, in0.z, __int_as_float(n0));
    nodeA1[n] = make_float4(in1.x, in1.y, in1.z, 0.f);
    nodeB0[n] = make_float4(w0.x, w0.y, w0.z, __int_as_float(m0));
    nodeB1[n] = make_float4(w1.x, w1.y, w1.z, 0.f);
}

// ---------------- angles: node-array gathers, locked numerics ----------------
__global__ void k_angles(const int* __restrict__ ei, const int* __restrict__ ej,
                         const float* __restrict__ pos, const float* __restrict__ dist,
                         const float4* __restrict__ nodeA0, const float4* __restrict__ nodeA1,
                         const float4* __restrict__ nodeB0, const float4* __restrict__ nodeB1,
                         float* __restrict__ theta, float* __restrict__ phi,
                         float* __restrict__ tau, int E) {
    int e = blockIdx.x * blockDim.x + threadIdx.x;
    if (e >= E) return;
    int ii = ei[e], jj = ej[e];

    float4 A0 = nodeA0[ii];
    float4 A1 = nodeA1[ii];
    float4 B0 = nodeB0[jj];
    float4 B1 = nodeB1[jj];
    int n0 = __float_as_int(A0.w);
    int m0 = __float_as_int(B0.w);

    F3 in0; in0.x = A0.x; in0.y = A0.y; in0.z = A0.z;
    F3 in1; in1.x = A1.x; in1.y = A1.y; in1.z = A1.z;
    F3 w0;  w0.x = B0.x;  w0.y = B0.y;  w0.z = B0.z;
    F3 w1;  w1.x = B1.x;  w1.y = B1.y;  w1.z = B1.z;

    F3 iref = (n0 == jj) ? in1 : in0;
    F3 jref = (m0 == ii) ? w1 : w0;

    F3 p = subv(loadp(pos, jj), loadp(pos, ii));
    F3 mp;
    mp.x = -p.x; mp.y = -p.y; mp.z = -p.z;

    // theta
    float a = dotf(mp, in0);
    F3 c1 = crossc(mp, in0);
    float ssb = dotf(c1, c1);
    float b = (ssb == 0.f) ? 0.f : sqrt_cr(ssb);
    float th = safe_atan2(b, a);
    if (th < 0.f) th += PI_F;

    float dji = dist[e];

    // phi
    F3 pl2 = crossc(mp, in1);
    a = dotf(c1, pl2);
    F3 cc = crossc(c1, pl2);
    b = dotf(cc, p) / dji;
    float ph = safe_atan2(b, a);
    if (ph < 0.f) ph += PI_F;

    // tau
    F3 t1 = crossc(p, jref);
    F3 t2 = crossc(p, iref);
    a = dotf(t1, t2);
    cc = crossc(t1, t2);
    b = dotf(cc, p) / dji;
    float ta = safe_atan2(b, a);
    if (ta < 0.f) ta += PI_F;

    theta[e] = th;
    phi[e] = ph;
    tau[e] = ta;
}

// ---------------- embedding + swish (runs LAST: overwrites scratch) ----------------
__global__ void k_embed(const int* __restrict__ x, const float* __restrict__ w,
                        float* __restrict__ h, int total4) {
    int t = blockIdx.x * blockDim.x + threadIdx.x;
    if (t >= total4) return;
    int n = t >> 6;
    int c = t & 63;
    int row = x[n];
    float4 v = *reinterpret_cast<const float4*>(w + (size_t)row * HID + c * 4);
    float4 o;
    o.x = v.x / (1.f + expf(-v.x));
    o.y = v.y / (1.f + expf(-v.y));
    o.z = v.z / (1.f + expf(-v.z));
    o.w = v.w / (1.f + expf(-v.w));
    *reinterpret_cast<float4*>(h + (size_t)n * HID + c * 4) = o;
}

extern "C" void kernel_launch(void* const* d_in, const int* in_sizes, int n_in,
                              void* d_out, int out_size, void* d_ws, size_t ws_size,
                              hipStream_t stream) {
    const int* x = (const int*)d_in[0];
    const float* pos = (const float*)d_in[1];
    const int* eidx = (const int*)d_in[2];
    const float* emb = (const float*)d_in[3];

    const int N = in_sizes[0];
    const int E = in_sizes[2] / 2;
    const int* ei = eidx;
    const int* ej = eidx + E;

    float* out = (float*)d_out;
    float* out_h = out;
    float* out_dist = out + (size_t)N * HID;
    float* out_theta = out_dist + E;
    float* out_phi = out_theta + E;
    float* out_tau = out_phi + E;

    // scratch in h-region of d_out; k_embed runs last and overwrites it
    ull* minA = (ull*)out_h;                      // N
    ull* minB = minA + N;                         // N
    float4* nodeA0 = (float4*)(minB + N);         // N
    float4* nodeA1 = nodeA0 + N;
    float4* nodeB0 = nodeA1 + N;
    float4* nodeB1 = nodeB0 + N;
    int* a0i = (int*)(nodeB1 + N);                // N
    int* a0j = a0i + N;                           // N
    unsigned* flags = (unsigned*)(a0j + N);       // 2

    const int BS = 256;
    int gE = (E + BS - 1) / BS;
    int gN = (N + BS - 1) / BS;
    int total4 = N * (HID / 4);
    int gH = (total4 + BS - 1) / BS;

    k_init<<<gN, BS, 0, stream>>>(minA, minB, flags, N);
    k_pass1<<<gE, BS, 0, stream>>>(ei, ej, pos, out_dist, minA, minB, E);
    k_extract0<<<gN, BS, 0, stream>>>(minA, minB, a0i, a0j, flags, N);
    k_pass2<<<gE, BS, 0, stream>>>(ei, ej, out_dist, a0i, a0j, flags, minA, minB, E);
    k_extract1_prep<<<gN, BS, 0, stream>>>(minA, minB, a0i, a0j, ei, ej, pos,
                                           nodeA0, nodeA1, nodeB0, nodeB1, N);
    k_angles<<<gE, BS, 0, stream>>>(ei, ej, pos, out_dist,
                                    nodeA0, nodeA1, nodeB0, nodeB1,
                                    out_theta, out_phi, out_tau, E);
    k_embed<<<gH, BS, 0, stream>>>(x, emb, out_h, total4);
}

// Round 17
// 558.932 us; speedup vs baseline: 2.1710x; 1.0013x over previous
//
#include <hip/hip_runtime.h>
#include <math.h>

#define HID 256
#define PI_F 3.14159265358979323846f
typedef unsigned long long ull;

struct F3 { float x, y, z; };

// ---- LOCKED NUMERICS (passing recipe, R14): clean dist (no FMA, numpy order,
// CR sqrt) + contracted crosses (fma(a.y,b.z,-(a.z*b.y))) + clean dots ----
__device__ __forceinline__ F3 crossc(F3 a, F3 b) {
    F3 r;
    float t1 = a.z * b.y;
    r.x = __builtin_fmaf(a.y, b.z, -t1);
    float t2 = a.x * b.z;
    r.y = __builtin_fmaf(a.z, b.x, -t2);
    float t3 = a.y * b.x;
    r.z = __builtin_fmaf(a.x, b.y, -t3);
    return r;
}
__device__ __forceinline__ float dotf(F3 a, F3 b) {
#pragma clang fp contract(off)
    float px = a.x * b.x;
    float py = a.y * b.y;
    float pz = a.z * b.z;
    return (px + py) + pz;
}
__device__ __forceinline__ float sqrt_cr(float ss) {
    return (float)sqrt((double)ss);
}
__device__ __forceinline__ float safe_atan2(float b, float a) {
    float aa = (a == 0.f && b == 0.f) ? 1.f : a;
    return atan2f(b, aa);
}
__device__ __forceinline__ F3 loadp(const float* __restrict__ pos, int n) {
    F3 r;
    r.x = pos[3 * n + 0];
    r.y = pos[3 * n + 1];
    r.z = pos[3 * n + 2];
    return r;
}
__device__ __forceinline__ F3 subv(F3 a, F3 b) {
#pragma clang fp contract(off)
    F3 r;
    r.x = a.x - b.x;
    r.y = a.y - b.y;
    r.z = a.z - b.z;
    return r;
}

// ---------------- init ----------------
__global__ void k_init(ull* __restrict__ minA, ull* __restrict__ minB,
                       unsigned* __restrict__ flags, int N) {
    int n = blockIdx.x * blockDim.x + threadIdx.x;
    if (n < N) {
        minA[n] = ~0ull;
        minB[n] = ~0ull;
    }
    if (n == 0) {
        flags[0] = 0u;
        flags[1] = 0u;
    }
}

// ---------------- pass1: dist (locked numerics) + filtered packed argmin0 ----------------
// Filter uses PLAIN CACHED loads of the slots' hi words (stale-safe: hi word is
// monotone non-increasing under lex-min atomics, stale >= current, so skipping
// on strictly-greater can never drop a winner or a tie).
__global__ void k_pass1(const int* __restrict__ ei, const int* __restrict__ ej,
                        const float* __restrict__ pos, float* __restrict__ dist,
                        ull* __restrict__ minA, ull* __restrict__ minB, int E) {
#pragma clang fp contract(off)
    int e = blockIdx.x * blockDim.x + threadIdx.x;
    if (e >= E) return;
    int ii = ei[e], jj = ej[e];
    F3 v = subv(loadp(pos, jj), loadp(pos, ii));
    float sx = v.x * v.x;
    float sy = v.y * v.y;
    float sz = v.z * v.z;
    float ss = (sx + sy) + sz;
    float d = (ss == 0.f) ? 0.f : sqrt_cr(ss);
    dist[e] = d;
    unsigned db = __float_as_uint(d);
    ull key = ((ull)db << 32) | (unsigned)e;
    // issue both cached probes first (independent -> overlapped latency)
    unsigned hiA = ((const unsigned*)&minA[ii])[1];
    unsigned hiB = ((const unsigned*)&minB[jj])[1];
    if (db <= hiA) atomicMin(&minA[ii], key);
    if (db <= hiB) atomicMin(&minB[jj], key);
}

// ---------------- extract0: unpack, set empty-flags, reset for pass2 ----------------
__global__ void k_extract0(ull* __restrict__ minA, ull* __restrict__ minB,
                           int* __restrict__ a0i, int* __restrict__ a0j,
                           unsigned* __restrict__ flags, int N) {
    int n = blockIdx.x * blockDim.x + threadIdx.x;
    if (n >= N) return;
    ull kA = minA[n];
    if (kA == ~0ull) { a0i[n] = 0; atomicOr(&flags[0], 1u); }
    else             { a0i[n] = (int)(kA & 0xffffffffu); }
    ull kB = minB[n];
    if (kB == ~0ull) { a0j[n] = 0; atomicOr(&flags[1], 1u); }
    else             { a0j[n] = (int)(kB & 0xffffffffu); }
    minA[n] = ~0ull;
    minB[n] = ~0ull;
}

// ---------------- pass2: filtered packed argmin1 on dist1 = dist + 8*mark ----------------
__global__ void k_pass2(const int* __restrict__ ei, const int* __restrict__ ej,
                        const float* __restrict__ dist, const int* __restrict__ a0i,
                        const int* __restrict__ a0j, const unsigned* __restrict__ flags,
                        ull* __restrict__ minA, ull* __restrict__ minB, int E) {
#pragma clang fp contract(off)
    int e = blockIdx.x * blockDim.x + threadIdx.x;
    if (e >= E) return;
    int ii = ei[e], jj = ej[e];
    float d = dist[e];
    bool inA = (a0i[ii] == e) || (e == 0 && flags[0] != 0u);
    float dA = inA ? (d + 8.0f) : d;
    unsigned dbA = __float_as_uint(dA);
    bool inB = (a0j[jj] == e) || (e == 0 && flags[1] != 0u);
    float dB = inB ? (d + 8.0f) : d;
    unsigned dbB = __float_as_uint(dB);
    unsigned hiA = ((const unsigned*)&minA[ii])[1];
    unsigned hiB = ((const unsigned*)&minB[jj])[1];
    if (dbA <= hiA) atomicMin(&minA[ii], ((ull)dbA << 32) | (unsigned)e);
    if (dbB <= hiB) atomicMin(&minB[jj], ((ull)dbB << 32) | (unsigned)e);
}

// ---------------- extract1 + per-node vector precompute ----------------
__global__ void k_extract1_prep(const ull* __restrict__ minA, const ull* __restrict__ minB,
                                const int* __restrict__ a0i, const int* __restrict__ a0j,
                                const int* __restrict__ ei, const int* __restrict__ ej,
                                const float* __restrict__ pos,
                                float4* __restrict__ nodeA0, float4* __restrict__ nodeA1,
                                float4* __restrict__ nodeB0, float4* __restrict__ nodeB1,
                                int N) {
    int n = blockIdx.x * blockDim.x + threadIdx.x;
    if (n >= N) return;
    ull kA = minA[n];
    int a1A = (kA == ~0ull) ? 0 : (int)(kA & 0xffffffffu);
    ull kB = minB[n];
    int a1B = (kB == ~0ull) ? 0 : (int)(kB & 0xffffffffu);

    int e0 = a0i[n];
    F3 in0 = subv(loadp(pos, ej[e0]), loadp(pos, ei[e0]));
    int n0 = ej[e0];
    F3 in1 = subv(loadp(pos, ej[a1A]), loadp(pos, ei[a1A]));

    int f0 = a0j[n];
    F3 w0 = subv(loadp(pos, ej[f0]), loadp(pos, ei[f0]));
    int m0 = ei[f0];
    F3 w1 = subv(loadp(pos, ej[a1B]), loadp(pos, ei[a1B]));

    nodeA0[n] = make_float4(in0.x, in0.y, in0.z, __int_as_float(n0));
    nodeA1[n] = make_float4(in1.x, in1.y, in1.z, 0.f);
    nodeB0[n] = make_float4(w0.x, w0.y, w0.z, __int_as_float(m0));
    nodeB1[n] = make_float4(w1.x, w1.y, w1.z, 0.f);
}

// ---------------- angles: node-array gathers, locked numerics ----------------
__global__ void k_angles(const int* __restrict__ ei, const int* __restrict__ ej,
                         const float* __restrict__ pos, const float* __restrict__ dist,
                         const float4* __restrict__ nodeA0, const float4* __restrict__ nodeA1,
                         const float4* __restrict__ nodeB0, const float4* __restrict__ nodeB1,
                         float* __restrict__ theta, float* __restrict__ phi,
                         float* __restrict__ tau, int E) {
    int e = blockIdx.x * blockDim.x + threadIdx.x;
    if (e >= E) return;
    int ii = ei[e], jj = ej[e];

    float4 A0 = nodeA0[ii];
    float4 A1 = nodeA1[ii];
    float4 B0 = nodeB0[jj];
    float4 B1 = nodeB1[jj];
    int n0 = __float_as_int(A0.w);
    int m0 = __float_as_int(B0.w);

    F3 in0; in0.x = A0.x; in0.y = A0.y; in0.z = A0.z;
    F3 in1; in1.x = A1.x; in1.y = A1.y; in1.z = A1.z;
    F3 w0;  w0.x = B0.x;  w0.y = B0.y;  w0.z = B0.z;
    F3 w1;  w1.x = B1.x;  w1.y = B1.y;  w1.z = B1.z;

    F3 iref = (n0 == jj) ? in1 : in0;
    F3 jref = (m0 == ii) ? w1 : w0;

    F3 p = subv(loadp(pos, jj), loadp(pos, ii));
    F3 mp;
    mp.x = -p.x; mp.y = -p.y; mp.z = -p.z;

    // theta
    float a = dotf(mp, in0);
    F3 c1 = crossc(mp, in0);
    float ssb = dotf(c1, c1);
    float b = (ssb == 0.f) ? 0.f : sqrt_cr(ssb);
    float th = safe_atan2(b, a);
    if (th < 0.f) th += PI_F;

    float dji = dist[e];

    // phi
    F3 pl2 = crossc(mp, in1);
    a = dotf(c1, pl2);
    F3 cc = crossc(c1, pl2);
    b = dotf(cc, p) / dji;
    float ph = safe_atan2(b, a);
    if (ph < 0.f) ph += PI_F;

    // tau
    F3 t1 = crossc(p, jref);
    F3 t2 = crossc(p, iref);
    a = dotf(t1, t2);
    cc = crossc(t1, t2);
    b = dotf(cc, p) / dji;
    float ta = safe_atan2(b, a);
    if (ta < 0.f) ta += PI_F;

    theta[e] = th;
    phi[e] = ph;
    tau[e] = ta;
}

// ---------------- embedding + swish (runs LAST: overwrites scratch) ----------------
__global__ void k_embed(const int* __restrict__ x, const float* __restrict__ w,
                        float* __restrict__ h, int total4) {
    int t = blockIdx.x * blockDim.x + threadIdx.x;
    if (t >= total4) return;
    int n = t >> 6;
    int c = t & 63;
    int row = x[n];
    float4 v = *reinterpret_cast<const float4*>(w + (size_t)row * HID + c * 4);
    float4 o;
    o.x = v.x / (1.f + expf(-v.x));
    o.y = v.y / (1.f + expf(-v.y));
    o.z = v.z / (1.f + expf(-v.z));
    o.w = v.w / (1.f + expf(-v.w));
    *reinterpret_cast<float4*>(h + (size_t)n * HID + c * 4) = o;
}

extern "C" void kernel_launch(void* const* d_in, const int* in_sizes, int n_in,
                              void* d_out, int out_size, void* d_ws, size_t ws_size,
                              hipStream_t stream) {
    const int* x = (const int*)d_in[0];
    const float* pos = (const float*)d_in[1];
    const int* eidx = (const int*)d_in[2];
    const float* emb = (const float*)d_in[3];

    const int N = in_sizes[0];
    const int E = in_sizes[2] / 2;
    const int* ei = eidx;
    const int* ej = eidx + E;

    float* out = (float*)d_out;
    float* out_h = out;
    float* out_dist = out + (size_t)N * HID;
    float* out_theta = out_dist + E;
    float* out_phi = out_theta + E;
    float* out_tau = out_phi + E;

    // scratch in h-region of d_out; k_embed runs last and overwrites it
    ull* minA = (ull*)out_h;                      // N
    ull* minB = minA + N;                         // N
    float4* nodeA0 = (float4*)(minB + N);         // N
    float4* nodeA1 = nodeA0 + N;
    float4* nodeB0 = nodeA1 + N;
    float4* nodeB1 = nodeB0 + N;
    int* a0i = (int*)(nodeB1 + N);                // N
    int* a0j = a0i + N;                           // N
    unsigned* flags = (unsigned*)(a0j + N);       // 2

    const int BS = 256;
    int gE = (E + BS - 1) / BS;
    int gN = (N + BS - 1) / BS;
    int total4 = N * (HID / 4);
    int gH = (total4 + BS - 1) / BS;

    k_init<<<gN, BS, 0, stream>>>(minA, minB, flags, N);
    k_pass1<<<gE, BS, 0, stream>>>(ei, ej, pos, out_dist, minA, minB, E);
    k_extract0<<<gN, BS, 0, stream>>>(minA, minB, a0i, a0j, flags, N);
    k_pass2<<<gE, BS, 0, stream>>>(ei, ej, out_dist, a0i, a0j, flags, minA, minB, E);
    k_extract1_prep<<<gN, BS, 0, stream>>>(minA, minB, a0i, a0j, ei, ej, pos,
                                           nodeA0, nodeA1, nodeB0, nodeB1, N);
    k_angles<<<gE, BS, 0, stream>>>(ei, ej, pos, out_dist,
                                    nodeA0, nodeA1, nodeB0, nodeB1,
                                    out_theta, out_phi, out_tau, E);
    k_embed<<<gH, BS, 0, stream>>>(x, emb, out_h, total4);
}

// Round 18
// 471.920 us; speedup vs baseline: 2.5713x; 1.1844x over previous
//
#include <hip/hip_runtime.h>
#include <math.h>

#define HID 256
#define PI_F 3.14159265358979323846f
typedef unsigned long long ull;

struct F3 { float x, y, z; };

// ---- LOCKED NUMERICS (passing recipe, R14): clean dist (no FMA, numpy order,
// CR sqrt) + contracted crosses (fma(a.y,b.z,-(a.z*b.y))) + clean dots ----
__device__ __forceinline__ F3 crossc(F3 a, F3 b) {
    F3 r;
    float t1 = a.z * b.y;
    r.x = __builtin_fmaf(a.y, b.z, -t1);
    float t2 = a.x * b.z;
    r.y = __builtin_fmaf(a.z, b.x, -t2);
    float t3 = a.y * b.x;
    r.z = __builtin_fmaf(a.x, b.y, -t3);
    return r;
}
__device__ __forceinline__ float dotf(F3 a, F3 b) {
#pragma clang fp contract(off)
    float px = a.x * b.x;
    float py = a.y * b.y;
    float pz = a.z * b.z;
    return (px + py) + pz;
}
__device__ __forceinline__ float sqrt_cr(float ss) {
    return (float)sqrt((double)ss);
}
__device__ __forceinline__ float safe_atan2(float b, float a) {
    float aa = (a == 0.f && b == 0.f) ? 1.f : a;
    return atan2f(b, aa);
}
__device__ __forceinline__ F3 loadp(const float* __restrict__ pos, int n) {
    F3 r;
    r.x = pos[3 * n + 0];
    r.y = pos[3 * n + 1];
    r.z = pos[3 * n + 2];
    return r;
}
__device__ __forceinline__ F3 subv(F3 a, F3 b) {
#pragma clang fp contract(off)
    F3 r;
    r.x = a.x - b.x;
    r.y = a.y - b.y;
    r.z = a.z - b.z;
    return r;
}
__device__ __forceinline__ ull umin64(ull a, ull b) { return a < b ? a : b; }
__device__ __forceinline__ ull umax64(ull a, ull b) { return a > b ? a : b; }

// two-slot lex-min insert with stale-safe filter.
// Invariant after all inserts: slot1 = min key, slot2 = 2nd-min key.
// (every key not ending in slot1 is offered to slot2 at least once)
__device__ __forceinline__ void insert2(ull* __restrict__ s1, ull* __restrict__ s2,
                                        unsigned db, ull key) {
    unsigned hi2 = ((const unsigned*)s2)[1];   // stale >= current (monotone)
    if (db > hi2) return;                      // can't be in top-2: safe skip
    unsigned hi1 = ((const unsigned*)s1)[1];
    if (db <= hi1) {
        ull ret = atomicMin(s1, key);
        ull loser = umax64(ret, key);
        if (loser != ~0ull) atomicMin(s2, loser);
    } else {
        atomicMin(s2, key);
    }
}

// ---------------- init ----------------
__global__ void k_init(ull* __restrict__ m1A, ull* __restrict__ m2A,
                       ull* __restrict__ m1B, ull* __restrict__ m2B,
                       unsigned* __restrict__ flags, int N) {
    int n = blockIdx.x * blockDim.x + threadIdx.x;
    if (n < N) {
        m1A[n] = ~0ull; m2A[n] = ~0ull;
        m1B[n] = ~0ull; m2B[n] = ~0ull;
    }
    if (n == 0) { flags[0] = 0u; flags[1] = 0u; }
}

// ---------------- pass1: dist (locked) + top-2 argmin for A and B sides ----------------
__global__ void k_pass1(const int* __restrict__ ei, const int* __restrict__ ej,
                        const float* __restrict__ pos, float* __restrict__ dist,
                        ull* __restrict__ m1A, ull* __restrict__ m2A,
                        ull* __restrict__ m1B, ull* __restrict__ m2B, int E) {
#pragma clang fp contract(off)
    int e = blockIdx.x * blockDim.x + threadIdx.x;
    if (e >= E) return;
    int ii = ei[e], jj = ej[e];
    F3 v = subv(loadp(pos, jj), loadp(pos, ii));
    float sx = v.x * v.x;
    float sy = v.y * v.y;
    float sz = v.z * v.z;
    float ss = (sx + sy) + sz;
    float d = (ss == 0.f) ? 0.f : sqrt_cr(ss);
    dist[e] = d;
    unsigned db = __float_as_uint(d);
    ull key = ((ull)db << 32) | (unsigned)e;
    insert2(&m1A[ii], &m2A[ii], db, key);
    insert2(&m1B[jj], &m2B[jj], db, key);
}

// ---------------- prep: a0/a1 from top-2 + node vectors (no second edge sweep) ----------------
// argmin1 = lex-min( (bits(d0+8), a0), slot2 ) — bit-exact vs ref's dist+8 marking.
__global__ void k_prep(const ull* __restrict__ m1A, const ull* __restrict__ m2A,
                       const ull* __restrict__ m1B, const ull* __restrict__ m2B,
                       const int* __restrict__ ei, const int* __restrict__ ej,
                       const float* __restrict__ pos,
                       float4* __restrict__ nodeA0, float4* __restrict__ nodeA1,
                       float4* __restrict__ nodeB0, float4* __restrict__ nodeB1,
                       int* __restrict__ a0i, int* __restrict__ a0j,
                       unsigned* __restrict__ flags, int N) {
#pragma clang fp contract(off)
    int n = blockIdx.x * blockDim.x + threadIdx.x;
    if (n >= N) return;

    // A side
    ull k1 = m1A[n];
    int a0, a1;
    if (k1 == ~0ull) {
        a0 = 0; a1 = 0;
        atomicOr(&flags[0], 1u);
    } else {
        a0 = (int)(k1 & 0xffffffffu);
        float d0 = __uint_as_float((unsigned)(k1 >> 32));
        ull mkey = ((ull)__float_as_uint(d0 + 8.0f) << 32) | (unsigned)a0;
        ull k2 = m2A[n];
        if (k2 == ~0ull) a1 = a0;                       // 1-edge segment
        else a1 = (mkey < k2) ? a0 : (int)(k2 & 0xffffffffu);
    }
    a0i[n] = a0;
    F3 in0 = subv(loadp(pos, ej[a0]), loadp(pos, ei[a0]));
    int n0 = ej[a0];
    F3 in1 = subv(loadp(pos, ej[a1]), loadp(pos, ei[a1]));
    nodeA0[n] = make_float4(in0.x, in0.y, in0.z, __int_as_float(n0));
    nodeA1[n] = make_float4(in1.x, in1.y, in1.z, 0.f);

    // B side
    ull q1 = m1B[n];
    int b0, b1;
    if (q1 == ~0ull) {
        b0 = 0; b1 = 0;
        atomicOr(&flags[1], 1u);
    } else {
        b0 = (int)(q1 & 0xffffffffu);
        float d0 = __uint_as_float((unsigned)(q1 >> 32));
        ull mkey = ((ull)__float_as_uint(d0 + 8.0f) << 32) | (unsigned)b0;
        ull q2 = m2B[n];
        if (q2 == ~0ull) b1 = b0;
        else b1 = (mkey < q2) ? b0 : (int)(q2 & 0xffffffffu);
    }
    a0j[n] = b0;
    F3 w0 = subv(loadp(pos, ej[b0]), loadp(pos, ei[b0]));
    int m0 = ei[b0];
    F3 w1 = subv(loadp(pos, ej[b1]), loadp(pos, ei[b1]));
    nodeB0[n] = make_float4(w0.x, w0.y, w0.z, __int_as_float(m0));
    nodeB1[n] = make_float4(w1.x, w1.y, w1.z, 0.f);
}

// ---------------- fix: exact edge-0 marking when some segment is empty ----------------
// Ref: dist1 = dist.at[argmin0].set adds +8 at index 0 when any segment is empty
// (argmin0=0 there). That extra mark affects only segment ei[0] (A) / ej[0] (B).
// Recompute that one segment's argmin1 by brute scan. Never fires on this data.
__global__ void k_fix(const unsigned* __restrict__ flags,
                      const int* __restrict__ ei, const int* __restrict__ ej,
                      const float* __restrict__ dist,
                      const int* __restrict__ a0i, const int* __restrict__ a0j,
                      const float* __restrict__ pos,
                      float4* __restrict__ nodeA1, float4* __restrict__ nodeB1, int E) {
#pragma clang fp contract(off)
    __shared__ ull smin[256];
    int side = blockIdx.x;          // 0 = A, 1 = B
    if (flags[side] == 0u) return;
    const int* seg = (side == 0) ? ei : ej;
    int s = seg[0];
    int marked = (side == 0) ? a0i[s] : a0j[s];
    ull local = ~0ull;
    for (int e = threadIdx.x; e < E; e += 256) {
        if (seg[e] != s) continue;
        float d = dist[e];
        float dm = (e == marked || e == 0) ? (d + 8.0f) : d;
        ull key = ((ull)__float_as_uint(dm) << 32) | (unsigned)e;
        local = umin64(local, key);
    }
    smin[threadIdx.x] = local;
    __syncthreads();
    for (int w = 128; w > 0; w >>= 1) {
        if (threadIdx.x < w) smin[threadIdx.x] = umin64(smin[threadIdx.x], smin[threadIdx.x + w]);
        __syncthreads();
    }
    if (threadIdx.x == 0) {
        int a1 = (smin[0] == ~0ull) ? 0 : (int)(smin[0] & 0xffffffffu);
        F3 v = subv(loadp(pos, ej[a1]), loadp(pos, ei[a1]));
        if (side == 0) nodeA1[s] = make_float4(v.x, v.y, v.z, 0.f);
        else           nodeB1[s] = make_float4(v.x, v.y, v.z, 0.f);
    }
}

// ---------------- angles: node-array gathers, locked numerics ----------------
__global__ void k_angles(const int* __restrict__ ei, const int* __restrict__ ej,
                         const float* __restrict__ pos, const float* __restrict__ dist,
                         const float4* __restrict__ nodeA0, const float4* __restrict__ nodeA1,
                         const float4* __restrict__ nodeB0, const float4* __restrict__ nodeB1,
                         float* __restrict__ theta, float* __restrict__ phi,
                         float* __restrict__ tau, int E) {
    int e = blockIdx.x * blockDim.x + threadIdx.x;
    if (e >= E) return;
    int ii = ei[e], jj = ej[e];

    float4 A0 = nodeA0[ii];
    float4 A1 = nodeA1[ii];
    float4 B0 = nodeB0[jj];
    float4 B1 = nodeB1[jj];
    int n0 = __float_as_int(A0.w);
    int m0 = __float_as_int(B0.w);

    F3 in0; in0.x = A0.x; in0.y = A0.y; in0.z = A0.z;
    F3 in1; in1.x = A1.x; in1.y = A1.y; in1.z = A1.z;
    F3 w0;  w0.x = B0.x;  w0.y = B0.y;  w0.z = B0.z;
    F3 w1;  w1.x = B1.x;  w1.y = B1.y;  w1.z = B1.z;

    F3 iref = (n0 == jj) ? in1 : in0;
    F3 jref = (m0 == ii) ? w1 : w0;

    F3 p = subv(loadp(pos, jj), loadp(pos, ii));
    F3 mp;
    mp.x = -p.x; mp.y = -p.y; mp.z = -p.z;

    // theta
    float a = dotf(mp, in0);
    F3 c1 = crossc(mp, in0);
    float ssb = dotf(c1, c1);
    float b = (ssb == 0.f) ? 0.f : sqrt_cr(ssb);
    float th = safe_atan2(b, a);
    if (th < 0.f) th += PI_F;

    float dji = dist[e];

    // phi
    F3 pl2 = crossc(mp, in1);
    a = dotf(c1, pl2);
    F3 cc = crossc(c1, pl2);
    b = dotf(cc, p) / dji;
    float ph = safe_atan2(b, a);
    if (ph < 0.f) ph += PI_F;

    // tau
    F3 t1 = crossc(p, jref);
    F3 t2 = crossc(p, iref);
    a = dotf(t1, t2);
    cc = crossc(t1, t2);
    b = dotf(cc, p) / dji;
    float ta = safe_atan2(b, a);
    if (ta < 0.f) ta += PI_F;

    theta[e] = th;
    phi[e] = ph;
    tau[e] = ta;
}

// ---------------- embedding + swish (runs LAST: overwrites scratch) ----------------
__global__ void k_embed(const int* __restrict__ x, const float* __restrict__ w,
                        float* __restrict__ h, int total4) {
    int t = blockIdx.x * blockDim.x + threadIdx.x;
    if (t >= total4) return;
    int n = t >> 6;
    int c = t & 63;
    int row = x[n];
    float4 v = *reinterpret_cast<const float4*>(w + (size_t)row * HID + c * 4);
    float4 o;
    o.x = v.x / (1.f + expf(-v.x));
    o.y = v.y / (1.f + expf(-v.y));
    o.z = v.z / (1.f + expf(-v.z));
    o.w = v.w / (1.f + expf(-v.w));
    *reinterpret_cast<float4*>(h + (size_t)n * HID + c * 4) = o;
}

extern "C" void kernel_launch(void* const* d_in, const int* in_sizes, int n_in,
                              void* d_out, int out_size, void* d_ws, size_t ws_size,
                              hipStream_t stream) {
    const int* x = (const int*)d_in[0];
    const float* pos = (const float*)d_in[1];
    const int* eidx = (const int*)d_in[2];
    const float* emb = (const float*)d_in[3];

    const int N = in_sizes[0];
    const int E = in_sizes[2] / 2;
    const int* ei = eidx;
    const int* ej = eidx + E;

    float* out = (float*)d_out;
    float* out_h = out;
    float* out_dist = out + (size_t)N * HID;
    float* out_theta = out_dist + E;
    float* out_phi = out_theta + E;
    float* out_tau = out_phi + E;

    // scratch in h-region of d_out; k_embed runs last and overwrites it
    ull* m1A = (ull*)out_h;                       // N
    ull* m2A = m1A + N;                           // N
    ull* m1B = m2A + N;                           // N
    ull* m2B = m1B + N;                           // N
    float4* nodeA0 = (float4*)(m2B + N);          // N (32N bytes offset: 16-aligned)
    float4* nodeA1 = nodeA0 + N;
    float4* nodeB0 = nodeA1 + N;
    float4* nodeB1 = nodeB0 + N;
    int* a0i = (int*)(nodeB1 + N);                // N
    int* a0j = a0i + N;                           // N
    unsigned* flags = (unsigned*)(a0j + N);       // 2

    const int BS = 256;
    int gE = (E + BS - 1) / BS;
    int gN = (N + BS - 1) / BS;
    int total4 = N * (HID / 4);
    int gH = (total4 + BS - 1) / BS;

    k_init<<<gN, BS, 0, stream>>>(m1A, m2A, m1B, m2B, flags, N);
    k_pass1<<<gE, BS, 0, stream>>>(ei, ej, pos, out_dist, m1A, m2A, m1B, m2B, E);
    k_prep<<<gN, BS, 0, stream>>>(m1A, m2A, m1B, m2B, ei, ej, pos,
                                  nodeA0, nodeA1, nodeB0, nodeB1, a0i, a0j, flags, N);
    k_fix<<<2, BS, 0, stream>>>(flags, ei, ej, out_dist, a0i, a0j, pos,
                                nodeA1, nodeB1, E);
    k_angles<<<gE, BS, 0, stream>>>(ei, ej, pos, out_dist,
                                    nodeA0, nodeA1, nodeB0, nodeB1,
                                    out_theta, out_phi, out_tau, E);
    k_embed<<<gH, BS, 0, stream>>>(x, emb, out_h, total4);
}

// Round 19
// 462.882 us; speedup vs baseline: 2.6215x; 1.0195x over previous
//
#include <hip/hip_runtime.h>
#include <math.h>

#define HID 256
#define PI_F 3.14159265358979323846f
typedef unsigned long long ull;

struct F3 { float x, y, z; };

// ---- LOCKED NUMERICS (passing recipe, R14): clean dist (no FMA, numpy order,
// CR sqrt) + contracted crosses (fma(a.y,b.z,-(a.z*b.y))) + clean dots ----
__device__ __forceinline__ F3 crossc(F3 a, F3 b) {
    F3 r;
    float t1 = a.z * b.y;
    r.x = __builtin_fmaf(a.y, b.z, -t1);
    float t2 = a.x * b.z;
    r.y = __builtin_fmaf(a.z, b.x, -t2);
    float t3 = a.y * b.x;
    r.z = __builtin_fmaf(a.x, b.y, -t3);
    return r;
}
__device__ __forceinline__ float dotf(F3 a, F3 b) {
#pragma clang fp contract(off)
    float px = a.x * b.x;
    float py = a.y * b.y;
    float pz = a.z * b.z;
    return (px + py) + pz;
}
__device__ __forceinline__ float sqrt_cr(float ss) {
    return (float)sqrt((double)ss);
}
__device__ __forceinline__ float safe_atan2(float b, float a) {
    float aa = (a == 0.f && b == 0.f) ? 1.f : a;
    return atan2f(b, aa);
}
__device__ __forceinline__ F3 loadp(const float* __restrict__ pos, int n) {
    F3 r;
    r.x = pos[3 * n + 0];
    r.y = pos[3 * n + 1];
    r.z = pos[3 * n + 2];
    return r;
}
__device__ __forceinline__ F3 subv(F3 a, F3 b) {
#pragma clang fp contract(off)
    F3 r;
    r.x = a.x - b.x;
    r.y = a.y - b.y;
    r.z = a.z - b.z;
    return r;
}
__device__ __forceinline__ ull umin64(ull a, ull b) { return a < b ? a : b; }
__device__ __forceinline__ ull umax64(ull a, ull b) { return a > b ? a : b; }

// two-slot lex-min insert, slots INTERLEAVED at s[0]=min, s[1]=2nd-min (same
// cache line -> one fetch serves both probes and the atomics).
// Stale-safe filter: hi words monotone non-increasing; stale >= current, so
// skipping on strictly-greater can never drop a winner or a tie.
// Invariant: every key not ending in s[0] is offered to s[1] at least once.
__device__ __forceinline__ void insert2(ull* __restrict__ s, unsigned db, ull key) {
    unsigned hi2 = ((const unsigned*)s)[3];
    if (db > hi2) return;
    unsigned hi1 = ((const unsigned*)s)[1];
    if (db <= hi1) {
        ull ret = atomicMin(&s[0], key);
        ull loser = umax64(ret, key);
        if (loser != ~0ull) atomicMin(&s[1], loser);
    } else {
        atomicMin(&s[1], key);
    }
}

// ---------------- pass1: dist (locked) + top-2 argmin for A and B sides ----------------
__global__ void k_pass1(const int* __restrict__ ei, const int* __restrict__ ej,
                        const float* __restrict__ pos, float* __restrict__ dist,
                        ull* __restrict__ slotsA, ull* __restrict__ slotsB, int E) {
#pragma clang fp contract(off)
    int e = blockIdx.x * blockDim.x + threadIdx.x;
    if (e >= E) return;
    int ii = ei[e], jj = ej[e];
    F3 v = subv(loadp(pos, jj), loadp(pos, ii));
    float sx = v.x * v.x;
    float sy = v.y * v.y;
    float sz = v.z * v.z;
    float ss = (sx + sy) + sz;
    float d = (ss == 0.f) ? 0.f : sqrt_cr(ss);
    dist[e] = d;
    unsigned db = __float_as_uint(d);
    ull key = ((ull)db << 32) | (unsigned)e;
    insert2(&slotsA[2 * (size_t)ii], db, key);
    insert2(&slotsB[2 * (size_t)jj], db, key);
}

// ---------------- prep: a0/a1 from top-2 + node vectors ----------------
// argmin1 = lex-min( (bits(d0+8), a0), slot2 ) — bit-exact vs ref's dist+8 marking.
__global__ void k_prep(const ull* __restrict__ slotsA, const ull* __restrict__ slotsB,
                       const int* __restrict__ ei, const int* __restrict__ ej,
                       const float* __restrict__ pos,
                       float4* __restrict__ nodeA0, float4* __restrict__ nodeA1,
                       float4* __restrict__ nodeB0, float4* __restrict__ nodeB1,
                       int* __restrict__ a0i, int* __restrict__ a0j,
                       unsigned* __restrict__ flags, int N) {
#pragma clang fp contract(off)
    int n = blockIdx.x * blockDim.x + threadIdx.x;
    if (n >= N) return;

    // A side
    ull k1 = slotsA[2 * (size_t)n];
    int a0, a1;
    if (k1 == ~0ull) {
        a0 = 0; a1 = 0;
        atomicOr(&flags[0], 1u);
    } else {
        a0 = (int)(k1 & 0xffffffffu);
        float d0 = __uint_as_float((unsigned)(k1 >> 32));
        ull mkey = ((ull)__float_as_uint(d0 + 8.0f) << 32) | (unsigned)a0;
        ull k2 = slotsA[2 * (size_t)n + 1];
        if (k2 == ~0ull) a1 = a0;                       // 1-edge segment
        else a1 = (mkey < k2) ? a0 : (int)(k2 & 0xffffffffu);
    }
    a0i[n] = a0;
    F3 in0 = subv(loadp(pos, ej[a0]), loadp(pos, ei[a0]));
    int n0 = ej[a0];
    F3 in1 = subv(loadp(pos, ej[a1]), loadp(pos, ei[a1]));
    nodeA0[n] = make_float4(in0.x, in0.y, in0.z, __int_as_float(n0));
    nodeA1[n] = make_float4(in1.x, in1.y, in1.z, 0.f);

    // B side
    ull q1 = slotsB[2 * (size_t)n];
    int b0, b1;
    if (q1 == ~0ull) {
        b0 = 0; b1 = 0;
        atomicOr(&flags[1], 1u);
    } else {
        b0 = (int)(q1 & 0xffffffffu);
        float d0 = __uint_as_float((unsigned)(q1 >> 32));
        ull mkey = ((ull)__float_as_uint(d0 + 8.0f) << 32) | (unsigned)b0;
        ull q2 = slotsB[2 * (size_t)n + 1];
        if (q2 == ~0ull) b1 = b0;
        else b1 = (mkey < q2) ? b0 : (int)(q2 & 0xffffffffu);
    }
    a0j[n] = b0;
    F3 w0 = subv(loadp(pos, ej[b0]), loadp(pos, ei[b0]));
    int m0 = ei[b0];
    F3 w1 = subv(loadp(pos, ej[b1]), loadp(pos, ei[b1]));
    nodeB0[n] = make_float4(w0.x, w0.y, w0.z, __int_as_float(m0));
    nodeB1[n] = make_float4(w1.x, w1.y, w1.z, 0.f);
}

// ---------------- fix: exact edge-0 marking when some segment is empty ----------------
// (ref marks index 0 too when any segment is empty; affects only segment of
// edge 0 on that side; brute-rescan it. Never fires on this data.)
__global__ void k_fix(const unsigned* __restrict__ flags,
                      const int* __restrict__ ei, const int* __restrict__ ej,
                      const float* __restrict__ dist,
                      const int* __restrict__ a0i, const int* __restrict__ a0j,
                      const float* __restrict__ pos,
                      float4* __restrict__ nodeA1, float4* __restrict__ nodeB1, int E) {
#pragma clang fp contract(off)
    __shared__ ull smin[256];
    int side = blockIdx.x;          // 0 = A, 1 = B
    if (flags[side] == 0u) return;
    const int* seg = (side == 0) ? ei : ej;
    int s = seg[0];
    int marked = (side == 0) ? a0i[s] : a0j[s];
    ull local = ~0ull;
    for (int e = threadIdx.x; e < E; e += 256) {
        if (seg[e] != s) continue;
        float d = dist[e];
        float dm = (e == marked || e == 0) ? (d + 8.0f) : d;
        ull key = ((ull)__float_as_uint(dm) << 32) | (unsigned)e;
        local = umin64(local, key);
    }
    smin[threadIdx.x] = local;
    __syncthreads();
    for (int w = 128; w > 0; w >>= 1) {
        if (threadIdx.x < w) smin[threadIdx.x] = umin64(smin[threadIdx.x], smin[threadIdx.x + w]);
        __syncthreads();
    }
    if (threadIdx.x == 0) {
        int a1 = (smin[0] == ~0ull) ? 0 : (int)(smin[0] & 0xffffffffu);
        F3 v = subv(loadp(pos, ej[a1]), loadp(pos, ei[a1]));
        if (side == 0) nodeA1[s] = make_float4(v.x, v.y, v.z, 0.f);
        else           nodeB1[s] = make_float4(v.x, v.y, v.z, 0.f);
    }
}

// ---------------- angles: node-array gathers, locked numerics ----------------
__global__ void k_angles(const int* __restrict__ ei, const int* __restrict__ ej,
                         const float* __restrict__ pos, const float* __restrict__ dist,
                         const float4* __restrict__ nodeA0, const float4* __restrict__ nodeA1,
                         const float4* __restrict__ nodeB0, const float4* __restrict__ nodeB1,
                         float* __restrict__ theta, float* __restrict__ phi,
                         float* __restrict__ tau, int E) {
    int e = blockIdx.x * blockDim.x + threadIdx.x;
    if (e >= E) return;
    int ii = ei[e], jj = ej[e];

    float4 A0 = nodeA0[ii];
    float4 A1 = nodeA1[ii];
    float4 B0 = nodeB0[jj];
    float4 B1 = nodeB1[jj];
    int n0 = __float_as_int(A0.w);
    int m0 = __float_as_int(B0.w);

    F3 in0; in0.x = A0.x; in0.y = A0.y; in0.z = A0.z;
    F3 in1; in1.x = A1.x; in1.y = A1.y; in1.z = A1.z;
    F3 w0;  w0.x = B0.x;  w0.y = B0.y;  w0.z = B0.z;
    F3 w1;  w1.x = B1.x;  w1.y = B1.y;  w1.z = B1.z;

    F3 iref = (n0 == jj) ? in1 : in0;
    F3 jref = (m0 == ii) ? w1 : w0;

    F3 p = subv(loadp(pos, jj), loadp(pos, ii));
    F3 mp;
    mp.x = -p.x; mp.y = -p.y; mp.z = -p.z;

    // theta
    float a = dotf(mp, in0);
    F3 c1 = crossc(mp, in0);
    float ssb = dotf(c1, c1);
    float b = (ssb == 0.f) ? 0.f : sqrt_cr(ssb);
    float th = safe_atan2(b, a);
    if (th < 0.f) th += PI_F;

    float dji = dist[e];

    // phi
    F3 pl2 = crossc(mp, in1);
    a = dotf(c1, pl2);
    F3 cc = crossc(c1, pl2);
    b = dotf(cc, p) / dji;
    float ph = safe_atan2(b, a);
    if (ph < 0.f) ph += PI_F;

    // tau
    F3 t1 = crossc(p, jref);
    F3 t2 = crossc(p, iref);
    a = dotf(t1, t2);
    cc = crossc(t1, t2);
    b = dotf(cc, p) / dji;
    float ta = safe_atan2(b, a);
    if (ta < 0.f) ta += PI_F;

    theta[e] = th;
    phi[e] = ph;
    tau[e] = ta;
}

// ---------------- embedding + swish (runs LAST: overwrites scratch) ----------------
__global__ void k_embed(const int* __restrict__ x, const float* __restrict__ w,
                        float* __restrict__ h, int total4) {
    int t = blockIdx.x * blockDim.x + threadIdx.x;
    if (t >= total4) return;
    int n = t >> 6;
    int c = t & 63;
    int row = x[n];
    float4 v = *reinterpret_cast<const float4*>(w + (size_t)row * HID + c * 4);
    float4 o;
    o.x = v.x / (1.f + expf(-v.x));
    o.y = v.y / (1.f + expf(-v.y));
    o.z = v.z / (1.f + expf(-v.z));
    o.w = v.w / (1.f + expf(-v.w));
    *reinterpret_cast<float4*>(h + (size_t)n * HID + c * 4) = o;
}

extern "C" void kernel_launch(void* const* d_in, const int* in_sizes, int n_in,
                              void* d_out, int out_size, void* d_ws, size_t ws_size,
                              hipStream_t stream) {
    const int* x = (const int*)d_in[0];
    const float* pos = (const float*)d_in[1];
    const int* eidx = (const int*)d_in[2];
    const float* emb = (const float*)d_in[3];

    const int N = in_sizes[0];
    const int E = in_sizes[2] / 2;
    const int* ei = eidx;
    const int* ej = eidx + E;

    float* out = (float*)d_out;
    float* out_h = out;
    float* out_dist = out + (size_t)N * HID;
    float* out_theta = out_dist + E;
    float* out_phi = out_theta + E;
    float* out_tau = out_phi + E;

    // scratch in h-region of d_out; k_embed runs last and overwrites it
    ull* slotsA = (ull*)out_h;                    // 2N (interleaved min/2nd-min)
    ull* slotsB = slotsA + 2 * (size_t)N;         // 2N
    float4* nodeA0 = (float4*)(slotsB + 2 * (size_t)N);
    float4* nodeA1 = nodeA0 + N;
    float4* nodeB0 = nodeA1 + N;
    float4* nodeB1 = nodeB0 + N;
    int* a0i = (int*)(nodeB1 + N);                // N
    int* a0j = a0i + N;                           // N
    unsigned* flags = (unsigned*)(a0j + N);       // 2

    const int BS = 256;
    int gE = (E + BS - 1) / BS;
    int gN = (N + BS - 1) / BS;
    int total4 = N * (HID / 4);
    int gH = (total4 + BS - 1) / BS;

    // init: 0xFF fill == ~0ull sentinels; flags zeroed
    hipMemsetAsync(slotsA, 0xFF, 4 * (size_t)N * sizeof(ull), stream);
    hipMemsetAsync(flags, 0, 2 * sizeof(unsigned), stream);

    k_pass1<<<gE, BS, 0, stream>>>(ei, ej, pos, out_dist, slotsA, slotsB, E);
    k_prep<<<gN, BS, 0, stream>>>(slotsA, slotsB, ei, ej, pos,
                                  nodeA0, nodeA1, nodeB0, nodeB1, a0i, a0j, flags, N);
    k_fix<<<2, BS, 0, stream>>>(flags, ei, ej, out_dist, a0i, a0j, pos,
                                nodeA1, nodeB1, E);
    k_angles<<<gE, BS, 0, stream>>>(ei, ej, pos, out_dist,
                                    nodeA0, nodeA1, nodeB0, nodeB1,
                                    out_theta, out_phi, out_tau, E);
    k_embed<<<gH, BS, 0, stream>>>(x, emb, out_h, total4);
}

// Round 20
// 410.529 us; speedup vs baseline: 2.9558x; 1.1275x over previous
//
#include <hip/hip_runtime.h>
#include <math.h>

#define HID 256
#define PI_F 3.14159265358979323846f
typedef unsigned long long ull;

struct F3 { float x, y, z; };

// ---- LOCKED NUMERICS (passing recipe, R14): clean dist (no FMA, numpy order,
// CR sqrt) + contracted crosses (fma(a.y,b.z,-(a.z*b.y))) + clean dots ----
__device__ __forceinline__ F3 crossc(F3 a, F3 b) {
    F3 r;
    float t1 = a.z * b.y;
    r.x = __builtin_fmaf(a.y, b.z, -t1);
    float t2 = a.x * b.z;
    r.y = __builtin_fmaf(a.z, b.x, -t2);
    float t3 = a.y * b.x;
    r.z = __builtin_fmaf(a.x, b.y, -t3);
    return r;
}
__device__ __forceinline__ float dotf(F3 a, F3 b) {
#pragma clang fp contract(off)
    float px = a.x * b.x;
    float py = a.y * b.y;
    float pz = a.z * b.z;
    return (px + py) + pz;
}
__device__ __forceinline__ float sqrt_cr(float ss) {
    return (float)sqrt((double)ss);
}
__device__ __forceinline__ float safe_atan2(float b, float a) {
    float aa = (a == 0.f && b == 0.f) ? 1.f : a;
    return atan2f(b, aa);
}
__device__ __forceinline__ F3 loadp(const float* __restrict__ pos, int n) {
    F3 r;
    r.x = pos[3 * n + 0];
    r.y = pos[3 * n + 1];
    r.z = pos[3 * n + 2];
    return r;
}
__device__ __forceinline__ F3 subv(F3 a, F3 b) {
#pragma clang fp contract(off)
    F3 r;
    r.x = a.x - b.x;
    r.y = a.y - b.y;
    r.z = a.z - b.z;
    return r;
}
__device__ __forceinline__ ull umin64(ull a, ull b) { return a < b ? a : b; }
__device__ __forceinline__ ull umax64(ull a, ull b) { return a > b ? a : b; }

// two-slot lex-min insert, slots interleaved (s[0]=min, s[1]=2nd-min).
// Stale-safe filter: hi words monotone non-increasing; stale >= current.
__device__ __forceinline__ void insert2(ull* __restrict__ s, unsigned db, ull key) {
    unsigned hi2 = ((const unsigned*)s)[3];
    if (db > hi2) return;
    unsigned hi1 = ((const unsigned*)s)[1];
    if (db <= hi1) {
        ull ret = atomicMin(&s[0], key);
        ull loser = umax64(ret, key);
        if (loser != ~0ull) atomicMin(&s[1], loser);
    } else {
        atomicMin(&s[1], key);
    }
}

// ---------------- pass1: dist (locked) + top-2 argmin for A and B sides ----------------
__global__ void k_pass1(const int* __restrict__ ei, const int* __restrict__ ej,
                        const float* __restrict__ pos, float* __restrict__ dist,
                        ull* __restrict__ slotsA, ull* __restrict__ slotsB, int E) {
#pragma clang fp contract(off)
    int e = blockIdx.x * blockDim.x + threadIdx.x;
    if (e >= E) return;
    int ii = ei[e], jj = ej[e];
    F3 v = subv(loadp(pos, jj), loadp(pos, ii));
    float sx = v.x * v.x;
    float sy = v.y * v.y;
    float sz = v.z * v.z;
    float ss = (sx + sy) + sz;
    float d = (ss == 0.f) ? 0.f : sqrt_cr(ss);
    dist[e] = d;
    unsigned db = __float_as_uint(d);
    ull key = ((ull)db << 32) | (unsigned)e;
    insert2(&slotsA[2 * (size_t)ii], db, key);
    insert2(&slotsB[2 * (size_t)jj], db, key);
}

// ---------------- prep: a0/a1 from top-2 + PAIRED node records ----------------
// nodeI[2n] = {in0.xyz, bits(n0)}, nodeI[2n+1] = {in1.xyz, 0}   (A side, same 32B)
// nodeJ[2n] = {w0.xyz,  bits(m0)}, nodeJ[2n+1] = {w1.xyz,  0}   (B side, same 32B)
// argmin1 = lex-min( (bits(d0+8), a0), slot2 ) — bit-exact vs ref's dist+8 marking.
__global__ void k_prep(const ull* __restrict__ slotsA, const ull* __restrict__ slotsB,
                       const int* __restrict__ ei, const int* __restrict__ ej,
                       const float* __restrict__ pos,
                       float4* __restrict__ nodeI, float4* __restrict__ nodeJ,
                       int* __restrict__ a0i, int* __restrict__ a0j,
                       unsigned* __restrict__ flags, int N) {
#pragma clang fp contract(off)
    int n = blockIdx.x * blockDim.x + threadIdx.x;
    if (n >= N) return;

    // A side
    ull k1 = slotsA[2 * (size_t)n];
    int a0, a1;
    if (k1 == ~0ull) {
        a0 = 0; a1 = 0;
        atomicOr(&flags[0], 1u);
    } else {
        a0 = (int)(k1 & 0xffffffffu);
        float d0 = __uint_as_float((unsigned)(k1 >> 32));
        ull mkey = ((ull)__float_as_uint(d0 + 8.0f) << 32) | (unsigned)a0;
        ull k2 = slotsA[2 * (size_t)n + 1];
        if (k2 == ~0ull) a1 = a0;                       // 1-edge segment
        else a1 = (mkey < k2) ? a0 : (int)(k2 & 0xffffffffu);
    }
    a0i[n] = a0;
    F3 in0 = subv(loadp(pos, ej[a0]), loadp(pos, ei[a0]));
    int n0 = ej[a0];
    F3 in1 = subv(loadp(pos, ej[a1]), loadp(pos, ei[a1]));
    nodeI[2 * (size_t)n]     = make_float4(in0.x, in0.y, in0.z, __int_as_float(n0));
    nodeI[2 * (size_t)n + 1] = make_float4(in1.x, in1.y, in1.z, 0.f);

    // B side
    ull q1 = slotsB[2 * (size_t)n];
    int b0, b1;
    if (q1 == ~0ull) {
        b0 = 0; b1 = 0;
        atomicOr(&flags[1], 1u);
    } else {
        b0 = (int)(q1 & 0xffffffffu);
        float d0 = __uint_as_float((unsigned)(q1 >> 32));
        ull mkey = ((ull)__float_as_uint(d0 + 8.0f) << 32) | (unsigned)b0;
        ull q2 = slotsB[2 * (size_t)n + 1];
        if (q2 == ~0ull) b1 = b0;
        else b1 = (mkey < q2) ? b0 : (int)(q2 & 0xffffffffu);
    }
    a0j[n] = b0;
    F3 w0 = subv(loadp(pos, ej[b0]), loadp(pos, ei[b0]));
    int m0 = ei[b0];
    F3 w1 = subv(loadp(pos, ej[b1]), loadp(pos, ei[b1]));
    nodeJ[2 * (size_t)n]     = make_float4(w0.x, w0.y, w0.z, __int_as_float(m0));
    nodeJ[2 * (size_t)n + 1] = make_float4(w1.x, w1.y, w1.z, 0.f);
}

// ---------------- fix: exact edge-0 marking when some segment is empty ----------------
// (never fires on this data; exact ref semantics if it does)
__global__ void k_fix(const unsigned* __restrict__ flags,
                      const int* __restrict__ ei, const int* __restrict__ ej,
                      const float* __restrict__ dist,
                      const int* __restrict__ a0i, const int* __restrict__ a0j,
                      const float* __restrict__ pos,
                      float4* __restrict__ nodeI, float4* __restrict__ nodeJ, int E) {
#pragma clang fp contract(off)
    __shared__ ull smin[256];
    int side = blockIdx.x;          // 0 = A, 1 = B
    if (flags[side] == 0u) return;
    const int* seg = (side == 0) ? ei : ej;
    int s = seg[0];
    int marked = (side == 0) ? a0i[s] : a0j[s];
    ull local = ~0ull;
    for (int e = threadIdx.x; e < E; e += 256) {
        if (seg[e] != s) continue;
        float d = dist[e];
        float dm = (e == marked || e == 0) ? (d + 8.0f) : d;
        ull key = ((ull)__float_as_uint(dm) << 32) | (unsigned)e;
        local = umin64(local, key);
    }
    smin[threadIdx.x] = local;
    __syncthreads();
    for (int w = 128; w > 0; w >>= 1) {
        if (threadIdx.x < w) smin[threadIdx.x] = umin64(smin[threadIdx.x], smin[threadIdx.x + w]);
        __syncthreads();
    }
    if (threadIdx.x == 0) {
        int a1 = (smin[0] == ~0ull) ? 0 : (int)(smin[0] & 0xffffffffu);
        F3 v = subv(loadp(pos, ej[a1]), loadp(pos, ei[a1]));
        if (side == 0) nodeI[2 * (size_t)s + 1] = make_float4(v.x, v.y, v.z, 0.f);
        else           nodeJ[2 * (size_t)s + 1] = make_float4(v.x, v.y, v.z, 0.f);
    }
}

// ---------------- angles: 2 paired-line gathers per edge, locked numerics ----------------
__global__ void k_angles(const int* __restrict__ ei, const int* __restrict__ ej,
                         const float* __restrict__ pos, const float* __restrict__ dist,
                         const float4* __restrict__ nodeI, const float4* __restrict__ nodeJ,
                         float* __restrict__ theta, float* __restrict__ phi,
                         float* __restrict__ tau, int E) {
    int e = blockIdx.x * blockDim.x + threadIdx.x;
    if (e >= E) return;
    int ii = ei[e], jj = ej[e];

    float4 A0 = nodeI[2 * (size_t)ii];
    float4 A1 = nodeI[2 * (size_t)ii + 1];
    float4 B0 = nodeJ[2 * (size_t)jj];
    float4 B1 = nodeJ[2 * (size_t)jj + 1];
    int n0 = __float_as_int(A0.w);
    int m0 = __float_as_int(B0.w);

    F3 in0; in0.x = A0.x; in0.y = A0.y; in0.z = A0.z;
    F3 in1; in1.x = A1.x; in1.y = A1.y; in1.z = A1.z;
    F3 w0;  w0.x = B0.x;  w0.y = B0.y;  w0.z = B0.z;
    F3 w1;  w1.x = B1.x;  w1.y = B1.y;  w1.z = B1.z;

    F3 iref = (n0 == jj) ? in1 : in0;
    F3 jref = (m0 == ii) ? w1 : w0;

    F3 p = subv(loadp(pos, jj), loadp(pos, ii));
    F3 mp;
    mp.x = -p.x; mp.y = -p.y; mp.z = -p.z;

    // theta
    float a = dotf(mp, in0);
    F3 c1 = crossc(mp, in0);
    float ssb = dotf(c1, c1);
    float b = (ssb == 0.f) ? 0.f : sqrt_cr(ssb);
    float th = safe_atan2(b, a);
    if (th < 0.f) th += PI_F;

    float dji = dist[e];

    // phi
    F3 pl2 = crossc(mp, in1);
    a = dotf(c1, pl2);
    F3 cc = crossc(c1, pl2);
    b = dotf(cc, p) / dji;
    float ph = safe_atan2(b, a);
    if (ph < 0.f) ph += PI_F;

    // tau
    F3 t1 = crossc(p, jref);
    F3 t2 = crossc(p, iref);
    a = dotf(t1, t2);
    cc = crossc(t1, t2);
    b = dotf(cc, p) / dji;
    float ta = safe_atan2(b, a);
    if (ta < 0.f) ta += PI_F;

    theta[e] = th;
    phi[e] = ph;
    tau[e] = ta;
}

// ---------------- embedding + swish (runs LAST: overwrites scratch) ----------------
__global__ void k_embed(const int* __restrict__ x, const float* __restrict__ w,
                        float* __restrict__ h, int total4) {
    int t = blockIdx.x * blockDim.x + threadIdx.x;
    if (t >= total4) return;
    int n = t >> 6;
    int c = t & 63;
    int row = x[n];
    float4 v = *reinterpret_cast<const float4*>(w + (size_t)row * HID + c * 4);
    float4 o;
    o.x = v.x / (1.f + expf(-v.x));
    o.y = v.y / (1.f + expf(-v.y));
    o.z = v.z / (1.f + expf(-v.z));
    o.w = v.w / (1.f + expf(-v.w));
    *reinterpret_cast<float4*>(h + (size_t)n * HID + c * 4) = o;
}

extern "C" void kernel_launch(void* const* d_in, const int* in_sizes, int n_in,
                              void* d_out, int out_size, void* d_ws, size_t ws_size,
                              hipStream_t stream) {
    const int* x = (const int*)d_in[0];
    const float* pos = (const float*)d_in[1];
    const int* eidx = (const int*)d_in[2];
    const float* emb = (const float*)d_in[3];

    const int N = in_sizes[0];
    const int E = in_sizes[2] / 2;
    const int* ei = eidx;
    const int* ej = eidx + E;

    float* out = (float*)d_out;
    float* out_h = out;
    float* out_dist = out + (size_t)N * HID;
    float* out_theta = out_dist + E;
    float* out_phi = out_theta + E;
    float* out_tau = out_phi + E;

    // scratch in h-region of d_out; k_embed runs last and overwrites it.
    // d_out is 256B-aligned; nodeI starts at byte offset 32N (32B-aligned) so
    // each {rec0,rec1} pair sits in one 64B-line-aligned 32B chunk.
    ull* slotsA = (ull*)out_h;                    // 2N (interleaved min/2nd-min)
    ull* slotsB = slotsA + 2 * (size_t)N;         // 2N
    float4* nodeI = (float4*)(slotsB + 2 * (size_t)N);   // 2N (paired A-side recs)
    float4* nodeJ = nodeI + 2 * (size_t)N;               // 2N (paired B-side recs)
    int* a0i = (int*)(nodeJ + 2 * (size_t)N);     // N
    int* a0j = a0i + N;                           // N
    unsigned* flags = (unsigned*)(a0j + N);       // 2

    const int BS = 256;
    int gE = (E + BS - 1) / BS;
    int gN = (N + BS - 1) / BS;
    int total4 = N * (HID / 4);
    int gH = (total4 + BS - 1) / BS;

    // init: 0xFF fill == ~0ull sentinels; flags zeroed
    hipMemsetAsync(slotsA, 0xFF, 4 * (size_t)N * sizeof(ull), stream);
    hipMemsetAsync(flags, 0, 2 * sizeof(unsigned), stream);

    k_pass1<<<gE, BS, 0, stream>>>(ei, ej, pos, out_dist, slotsA, slotsB, E);
    k_prep<<<gN, BS, 0, stream>>>(slotsA, slotsB, ei, ej, pos,
                                  nodeI, nodeJ, a0i, a0j, flags, N);
    k_fix<<<2, BS, 0, stream>>>(flags, ei, ej, out_dist, a0i, a0j, pos,
                                nodeI, nodeJ, E);
    k_angles<<<gE, BS, 0, stream>>>(ei, ej, pos, out_dist, nodeI, nodeJ,
                                    out_theta, out_phi, out_tau, E);
    k_embed<<<gH, BS, 0, stream>>>(x, emb, out_h, total4);
}

// Round 21
// 388.257 us; speedup vs baseline: 3.1254x; 1.0574x over previous
//
#include <hip/hip_runtime.h>
#include <math.h>

#define HID 256
#define PI_F 3.14159265358979323846f
typedef unsigned long long ull;

struct F3 { float x, y, z; };

// ---- LOCKED NUMERICS (passing recipe, R14): clean dist (no FMA, numpy order,
// CR sqrt) + contracted crosses (fma(a.y,b.z,-(a.z*b.y))) + clean dots ----
__device__ __forceinline__ F3 crossc(F3 a, F3 b) {
    F3 r;
    float t1 = a.z * b.y;
    r.x = __builtin_fmaf(a.y, b.z, -t1);
    float t2 = a.x * b.z;
    r.y = __builtin_fmaf(a.z, b.x, -t2);
    float t3 = a.y * b.x;
    r.z = __builtin_fmaf(a.x, b.y, -t3);
    return r;
}
__device__ __forceinline__ float dotf(F3 a, F3 b) {
#pragma clang fp contract(off)
    float px = a.x * b.x;
    float py = a.y * b.y;
    float pz = a.z * b.z;
    return (px + py) + pz;
}
__device__ __forceinline__ float sqrt_cr(float ss) {
    return (float)sqrt((double)ss);
}
__device__ __forceinline__ float safe_atan2(float b, float a) {
    float aa = (a == 0.f && b == 0.f) ? 1.f : a;
    return atan2f(b, aa);
}
__device__ __forceinline__ F3 loadp(const float* __restrict__ pos, int n) {
    F3 r;
    r.x = pos[3 * n + 0];
    r.y = pos[3 * n + 1];
    r.z = pos[3 * n + 2];
    return r;
}
__device__ __forceinline__ F3 subv(F3 a, F3 b) {
#pragma clang fp contract(off)
    F3 r;
    r.x = a.x - b.x;
    r.y = a.y - b.y;
    r.z = a.z - b.z;
    return r;
}
__device__ __forceinline__ ull umin64(ull a, ull b) { return a < b ? a : b; }
__device__ __forceinline__ ull umax64(ull a, ull b) { return a > b ? a : b; }

// two-slot lex-min insert, slots interleaved (s[0]=min, s[1]=2nd-min).
// Stale-safe filter: hi words monotone non-increasing; stale >= current.
// Invariant: every key not ending in s[0] is offered to s[1] at least once.
__device__ __forceinline__ void insert2(ull* __restrict__ s, unsigned db, ull key) {
    unsigned hi2 = ((const unsigned*)s)[3];
    if (db > hi2) return;
    unsigned hi1 = ((const unsigned*)s)[1];
    if (db <= hi1) {
        ull ret = atomicMin(&s[0], key);
        ull loser = umax64(ret, key);
        if (loser != ~0ull) atomicMin(&s[1], loser);
    } else {
        atomicMin(&s[1], key);
    }
}

// ---------------- pass1 chunk: dist (locked) + snapshot-filtered top-2 insert ----------------
// thrA/thrB are CLEAN (written only between chunks) -> L2-cacheable; a skip on
// db > thr is safe because thr >= current slot2-hi (monotone + stream order).
__global__ void k_pass1(const int* __restrict__ ei, const int* __restrict__ ej,
                        const float* __restrict__ pos, float* __restrict__ dist,
                        ull* __restrict__ slotsA, ull* __restrict__ slotsB,
                        const unsigned* __restrict__ thrA, const unsigned* __restrict__ thrB,
                        int e0, int e1) {
#pragma clang fp contract(off)
    int e = e0 + blockIdx.x * blockDim.x + threadIdx.x;
    if (e >= e1) return;
    int ii = ei[e], jj = ej[e];
    F3 v = subv(loadp(pos, jj), loadp(pos, ii));
    float sx = v.x * v.x;
    float sy = v.y * v.y;
    float sz = v.z * v.z;
    float ss = (sx + sy) + sz;
    float d = (ss == 0.f) ? 0.f : sqrt_cr(ss);
    dist[e] = d;
    unsigned db = __float_as_uint(d);
    ull key = ((ull)db << 32) | (unsigned)e;
    if (db <= thrA[ii]) insert2(&slotsA[2 * (size_t)ii], db, key);
    if (db <= thrB[jj]) insert2(&slotsB[2 * (size_t)jj], db, key);
}

// ---------------- snapshot: publish current 2nd-min dist-bits as clean thresholds ----------------
__global__ void k_snapshot(const ull* __restrict__ slotsA, const ull* __restrict__ slotsB,
                           unsigned* __restrict__ thrA, unsigned* __restrict__ thrB, int N) {
    int n = blockIdx.x * blockDim.x + threadIdx.x;
    if (n >= N) return;
    thrA[n] = (unsigned)(slotsA[2 * (size_t)n + 1] >> 32);
    thrB[n] = (unsigned)(slotsB[2 * (size_t)n + 1] >> 32);
}

// ---------------- prep: a0/a1 from top-2 + PAIRED node records ----------------
// argmin1 = lex-min( (bits(d0+8), a0), slot2 ) — bit-exact vs ref's dist+8 marking.
__global__ void k_prep(const ull* __restrict__ slotsA, const ull* __restrict__ slotsB,
                       const int* __restrict__ ei, const int* __restrict__ ej,
                       const float* __restrict__ pos,
                       float4* __restrict__ nodeI, float4* __restrict__ nodeJ,
                       int* __restrict__ a0i, int* __restrict__ a0j,
                       unsigned* __restrict__ flags, int N) {
#pragma clang fp contract(off)
    int n = blockIdx.x * blockDim.x + threadIdx.x;
    if (n >= N) return;

    // A side
    ull k1 = slotsA[2 * (size_t)n];
    int a0, a1;
    if (k1 == ~0ull) {
        a0 = 0; a1 = 0;
        atomicOr(&flags[0], 1u);
    } else {
        a0 = (int)(k1 & 0xffffffffu);
        float d0 = __uint_as_float((unsigned)(k1 >> 32));
        ull mkey = ((ull)__float_as_uint(d0 + 8.0f) << 32) | (unsigned)a0;
        ull k2 = slotsA[2 * (size_t)n + 1];
        if (k2 == ~0ull) a1 = a0;                       // 1-edge segment
        else a1 = (mkey < k2) ? a0 : (int)(k2 & 0xffffffffu);
    }
    a0i[n] = a0;
    F3 in0 = subv(loadp(pos, ej[a0]), loadp(pos, ei[a0]));
    int n0 = ej[a0];
    F3 in1 = subv(loadp(pos, ej[a1]), loadp(pos, ei[a1]));
    nodeI[2 * (size_t)n]     = make_float4(in0.x, in0.y, in0.z, __int_as_float(n0));
    nodeI[2 * (size_t)n + 1] = make_float4(in1.x, in1.y, in1.z, 0.f);

    // B side
    ull q1 = slotsB[2 * (size_t)n];
    int b0, b1;
    if (q1 == ~0ull) {
        b0 = 0; b1 = 0;
        atomicOr(&flags[1], 1u);
    } else {
        b0 = (int)(q1 & 0xffffffffu);
        float d0 = __uint_as_float((unsigned)(q1 >> 32));
        ull mkey = ((ull)__float_as_uint(d0 + 8.0f) << 32) | (unsigned)b0;
        ull q2 = slotsB[2 * (size_t)n + 1];
        if (q2 == ~0ull) b1 = b0;
        else b1 = (mkey < q2) ? b0 : (int)(q2 & 0xffffffffu);
    }
    a0j[n] = b0;
    F3 w0 = subv(loadp(pos, ej[b0]), loadp(pos, ei[b0]));
    int m0 = ei[b0];
    F3 w1 = subv(loadp(pos, ej[b1]), loadp(pos, ei[b1]));
    nodeJ[2 * (size_t)n]     = make_float4(w0.x, w0.y, w0.z, __int_as_float(m0));
    nodeJ[2 * (size_t)n + 1] = make_float4(w1.x, w1.y, w1.z, 0.f);
}

// ---------------- fix: exact edge-0 marking when some segment is empty ----------------
// (never fires on this data; exact ref semantics if it does)
__global__ void k_fix(const unsigned* __restrict__ flags,
                      const int* __restrict__ ei, const int* __restrict__ ej,
                      const float* __restrict__ dist,
                      const int* __restrict__ a0i, const int* __restrict__ a0j,
                      const float* __restrict__ pos,
                      float4* __restrict__ nodeI, float4* __restrict__ nodeJ, int E) {
#pragma clang fp contract(off)
    __shared__ ull smin[256];
    int side = blockIdx.x;          // 0 = A, 1 = B
    if (flags[side] == 0u) return;
    const int* seg = (side == 0) ? ei : ej;
    int s = seg[0];
    int marked = (side == 0) ? a0i[s] : a0j[s];
    ull local = ~0ull;
    for (int e = threadIdx.x; e < E; e += 256) {
        if (seg[e] != s) continue;
        float d = dist[e];
        float dm = (e == marked || e == 0) ? (d + 8.0f) : d;
        ull key = ((ull)__float_as_uint(dm) << 32) | (unsigned)e;
        local = umin64(local, key);
    }
    smin[threadIdx.x] = local;
    __syncthreads();
    for (int w = 128; w > 0; w >>= 1) {
        if (threadIdx.x < w) smin[threadIdx.x] = umin64(smin[threadIdx.x], smin[threadIdx.x + w]);
        __syncthreads();
    }
    if (threadIdx.x == 0) {
        int a1 = (smin[0] == ~0ull) ? 0 : (int)(smin[0] & 0xffffffffu);
        F3 v = subv(loadp(pos, ej[a1]), loadp(pos, ei[a1]));
        if (side == 0) nodeI[2 * (size_t)s + 1] = make_float4(v.x, v.y, v.z, 0.f);
        else           nodeJ[2 * (size_t)s + 1] = make_float4(v.x, v.y, v.z, 0.f);
    }
}

// ---------------- angles: 2 paired-line gathers per edge, locked numerics ----------------
__global__ void k_angles(const int* __restrict__ ei, const int* __restrict__ ej,
                         const float* __restrict__ pos, const float* __restrict__ dist,
                         const float4* __restrict__ nodeI, const float4* __restrict__ nodeJ,
                         float* __restrict__ theta, float* __restrict__ phi,
                         float* __restrict__ tau, int E) {
    int e = blockIdx.x * blockDim.x + threadIdx.x;
    if (e >= E) return;
    int ii = ei[e], jj = ej[e];

    float4 A0 = nodeI[2 * (size_t)ii];
    float4 A1 = nodeI[2 * (size_t)ii + 1];
    float4 B0 = nodeJ[2 * (size_t)jj];
    float4 B1 = nodeJ[2 * (size_t)jj + 1];
    int n0 = __float_as_int(A0.w);
    int m0 = __float_as_int(B0.w);

    F3 in0; in0.x = A0.x; in0.y = A0.y; in0.z = A0.z;
    F3 in1; in1.x = A1.x; in1.y = A1.y; in1.z = A1.z;
    F3 w0;  w0.x = B0.x;  w0.y = B0.y;  w0.z = B0.z;
    F3 w1;  w1.x = B1.x;  w1.y = B1.y;  w1.z = B1.z;

    F3 iref = (n0 == jj) ? in1 : in0;
    F3 jref = (m0 == ii) ? w1 : w0;

    F3 p = subv(loadp(pos, jj), loadp(pos, ii));
    F3 mp;
    mp.x = -p.x; mp.y = -p.y; mp.z = -p.z;

    // theta
    float a = dotf(mp, in0);
    F3 c1 = crossc(mp, in0);
    float ssb = dotf(c1, c1);
    float b = (ssb == 0.f) ? 0.f : sqrt_cr(ssb);
    float th = safe_atan2(b, a);
    if (th < 0.f) th += PI_F;

    float dji = dist[e];

    // phi
    F3 pl2 = crossc(mp, in1);
    a = dotf(c1, pl2);
    F3 cc = crossc(c1, pl2);
    b = dotf(cc, p) / dji;
    float ph = safe_atan2(b, a);
    if (ph < 0.f) ph += PI_F;

    // tau
    F3 t1 = crossc(p, jref);
    F3 t2 = crossc(p, iref);
    a = dotf(t1, t2);
    cc = crossc(t1, t2);
    b = dotf(cc, p) / dji;
    float ta = safe_atan2(b, a);
    if (ta < 0.f) ta += PI_F;

    theta[e] = th;
    phi[e] = ph;
    tau[e] = ta;
}

// ---------------- embedding + swish (runs LAST: overwrites scratch) ----------------
__global__ void k_embed(const int* __restrict__ x, const float* __restrict__ w,
                        float* __restrict__ h, int total4) {
    int t = blockIdx.x * blockDim.x + threadIdx.x;
    if (t >= total4) return;
    int n = t >> 6;
    int c = t & 63;
    int row = x[n];
    float4 v = *reinterpret_cast<const float4*>(w + (size_t)row * HID + c * 4);
    float4 o;
    o.x = v.x / (1.f + expf(-v.x));
    o.y = v.y / (1.f + expf(-v.y));
    o.z = v.z / (1.f + expf(-v.z));
    o.w = v.w / (1.f + expf(-v.w));
    *reinterpret_cast<float4*>(h + (size_t)n * HID + c * 4) = o;
}

extern "C" void kernel_launch(void* const* d_in, const int* in_sizes, int n_in,
                              void* d_out, int out_size, void* d_ws, size_t ws_size,
                              hipStream_t stream) {
    const int* x = (const int*)d_in[0];
    const float* pos = (const float*)d_in[1];
    const int* eidx = (const int*)d_in[2];
    const float* emb = (const float*)d_in[3];

    const int N = in_sizes[0];
    const int E = in_sizes[2] / 2;
    const int* ei = eidx;
    const int* ej = eidx + E;

    float* out = (float*)d_out;
    float* out_h = out;
    float* out_dist = out + (size_t)N * HID;
    float* out_theta = out_dist + E;
    float* out_phi = out_theta + E;
    float* out_tau = out_phi + E;

    // scratch in h-region of d_out; k_embed runs last and overwrites it.
    ull* slotsA = (ull*)out_h;                    // 2N (interleaved min/2nd-min)
    ull* slotsB = slotsA + 2 * (size_t)N;         // 2N
    unsigned* thrA = (unsigned*)(slotsB + 2 * (size_t)N);   // N (clean snapshots)
    unsigned* thrB = thrA + N;                    // N
    float4* nodeI = (float4*)(thrB + N);          // 2N (paired A-side recs; offset 40N B, 16-aligned)
    float4* nodeJ = nodeI + 2 * (size_t)N;        // 2N
    int* a0i = (int*)(nodeJ + 2 * (size_t)N);     // N
    int* a0j = a0i + N;                           // N
    unsigned* flags = (unsigned*)(a0j + N);       // 2

    const int BS = 256;
    int gN = (N + BS - 1) / BS;
    int total4 = N * (HID / 4);
    int gH = (total4 + BS - 1) / BS;

    // init: 0xFF fill covers slotsA/slotsB sentinels AND thrA/thrB (=UINT_MAX,
    // pass-all for chunk 1); flags zeroed.
    hipMemsetAsync(slotsA, 0xFF, 4 * (size_t)N * sizeof(ull) + 2 * (size_t)N * sizeof(unsigned), stream);
    hipMemsetAsync(flags, 0, 2 * sizeof(unsigned), stream);

    // geometric chunks: 1/16, 1/16, 1/8, 1/4, rest; snapshot between chunks
    int c0 = 0, c1 = E / 16, c2 = E / 8, c3 = E / 4, c4 = E / 2, c5 = E;
    int bounds[6] = {c0, c1, c2, c3, c4, c5};
    for (int k = 0; k < 5; k++) {
        int lo = bounds[k], hi = bounds[k + 1];
        if (hi <= lo) continue;
        int g = (hi - lo + BS - 1) / BS;
        k_pass1<<<g, BS, 0, stream>>>(ei, ej, pos, out_dist, slotsA, slotsB,
                                      thrA, thrB, lo, hi);
        if (k < 4)
            k_snapshot<<<gN, BS, 0, stream>>>(slotsA, slotsB, thrA, thrB, N);
    }

    k_prep<<<gN, BS, 0, stream>>>(slotsA, slotsB, ei, ej, pos,
                                  nodeI, nodeJ, a0i, a0j, flags, N);
    k_fix<<<2, BS, 0, stream>>>(flags, ei, ej, out_dist, a0i, a0j, pos,
                                nodeI, nodeJ, E);
    k_angles<<<(E + BS - 1) / BS, BS, 0, stream>>>(ei, ej, pos, out_dist, nodeI, nodeJ,
                                                   out_theta, out_phi, out_tau, E);
    k_embed<<<gH, BS, 0, stream>>>(x, emb, out_h, total4);
}